// Round 1
// baseline (694.392 us; speedup 1.0000x reference)
//
#include <hip/hip_runtime.h>
#include <cstdint>

typedef unsigned short u16;
typedef __attribute__((ext_vector_type(8))) short short8;
typedef __attribute__((ext_vector_type(8))) __bf16 bf16x8;
typedef __attribute__((ext_vector_type(4))) float f32x4;

#define DEV __device__ __forceinline__

DEV u16 f2bf(float f){
  uint32_t u = __float_as_uint(f);
  u += 0x7fffu + ((u >> 16) & 1u);
  return (u16)(u >> 16);
}
DEV float bf2f(u16 h){ return __uint_as_float(((uint32_t)h) << 16); }

DEV f32x4 mfma16(short8 a, short8 b, f32x4 c){
  return __builtin_amdgcn_mfma_f32_16x16x32_bf16(
      __builtin_bit_cast(bf16x8, a), __builtin_bit_cast(bf16x8, b), c, 0, 0, 0);
}

#define NN 10000
#define EE 160000
#define MPN 10112   /* 79*128  */
#define MPE 160128  /* 1251*128 */

// ---------------- utility kernels ----------------
__global__ void conv_bf16_k(const float* __restrict__ in, u16* __restrict__ out,
                            int n_in, int n_tot){
  int i = blockIdx.x * 256 + threadIdx.x;
  if(i < n_tot) out[i] = (i < n_in) ? f2bf(in[i]) : (u16)0;
}

__global__ void count_k(const int* __restrict__ dst, int* __restrict__ cnt){
  int i = blockIdx.x * 256 + threadIdx.x;
  if(i < EE) atomicAdd(&cnt[dst[i]], 1);
}

__global__ void scan_k(const int* __restrict__ cnt, int* __restrict__ offs,
                       int* __restrict__ cursor){
  __shared__ int buf[256];
  __shared__ int carry;
  int tid = threadIdx.x;
  if(tid == 0) carry = 0;
  __syncthreads();
  for(int base = 0; base < NN; base += 256){
    int i = base + tid;
    int v = (i < NN) ? cnt[i] : 0;
    buf[tid] = v; __syncthreads();
    for(int d = 1; d < 256; d <<= 1){
      int t = (tid >= d) ? buf[tid - d] : 0;
      __syncthreads();
      buf[tid] += t;
      __syncthreads();
    }
    int excl = carry + buf[tid] - v;
    if(i < NN){ offs[i] = excl; cursor[i] = excl; }
    __syncthreads();
    if(tid == 0) carry += buf[255];
    __syncthreads();
  }
  if(tid == 0) offs[NN] = carry;
}

__global__ void scatter_k(const int* __restrict__ dst, int* __restrict__ cursor,
                          int* __restrict__ eids){
  int i = blockIdx.x * 256 + threadIdx.x;
  if(i < EE){ int p = atomicAdd(&cursor[dst[i]], 1); eids[p] = i; }
}

__global__ void sortfin_k(const int* __restrict__ offs, int* __restrict__ eids,
                          const int* __restrict__ src, int* __restrict__ slotOf,
                          int* __restrict__ srcp){
  int n = blockIdx.x * 256 + threadIdx.x;
  if(n >= NN) return;
  int p0 = offs[n], p1 = offs[n + 1];
  for(int i = p0 + 1; i < p1; ++i){          // deterministic order = edge-id order
    int key = eids[i]; int j = i - 1;
    while(j >= p0 && eids[j] > key){ eids[j + 1] = eids[j]; --j; }
    eids[j + 1] = key;
  }
  for(int p = p0; p < p1; ++p){ int e = eids[p]; slotOf[e] = p; srcp[p] = src[e]; }
}

// ---------------- weight prep ----------------
struct WPack {
  const float* Wq[3]; const float* Wk[3]; const float* Wv[3];
  const float* Ws[3]; const float* We[3];
  const float* bq[3]; const float* bk[3]; const float* bv[3]; const float* bs[3];
};

// Wcat layout per layer: rows [0,256) Wq^T, [256,512) Wk^T, [512,768) Wv^T,
// [768,1024) Ws^T, [1024,1280) (Wq@We^T)^T ; each row has K=256 contiguous.
__global__ __launch_bounds__(256) void prepw_k(WPack P, u16* __restrict__ Wcat,
                                               u16* __restrict__ Wet){
  __shared__ float we[256];
  int b = blockIdx.x; int l = b / 1536, r = b % 1536; int k = threadIdx.x;
  if(r < 1280){
    int sec = r >> 8, n = r & 255; float v;
    if(sec == 0)      v = P.Wq[l][k * 256 + n];
    else if(sec == 1) v = P.Wk[l][k * 256 + n];
    else if(sec == 2) v = P.Wv[l][k * 256 + n];
    else if(sec == 3) v = P.Ws[l][k * 256 + n];
    else{
      we[k] = P.We[l][n * 256 + k];
      __syncthreads();
      const float* wq = P.Wq[l] + (size_t)k * 256;
      float s = 0.f;
      #pragma unroll 4
      for(int c = 0; c < 256; ++c) s += wq[c] * we[c];
      v = s;
    }
    Wcat[((size_t)l * 1280 + r) * 256 + k] = f2bf(v);
  } else {
    int n = r - 1280;
    Wet[((size_t)l * 256 + n) * 256 + k] = f2bf(P.We[l][k * 256 + n]);
  }
}

__global__ void prepbias_k(WPack P, float* __restrict__ bias_cat){
  int b = blockIdx.x; int l = b / 5, seg = b % 5; int t = threadIdx.x;
  float v;
  if(seg == 0)      v = P.bq[l][t];
  else if(seg == 1) v = P.bk[l][t];
  else if(seg == 2) v = P.bv[l][t];
  else if(seg == 3) v = P.bs[l][t];
  else{
    const float* we = P.We[l] + (size_t)t * 256; const float* bq = P.bq[l];
    float s = 0.f;
    for(int c = 0; c < 256; ++c) s += bq[c] * we[c];
    v = s;
  }
  bias_cat[(size_t)l * 1280 + seg * 256 + t] = v;
}

__global__ void prepenc_k(const float* __restrict__ Wne, const float* __restrict__ Wee,
                          u16* __restrict__ Wnet, u16* __restrict__ Weet){
  int n = blockIdx.x, t = threadIdx.x;   // grid 256, block 128
  Wnet[n * 128 + t] = f2bf(Wne[(size_t)t * 256 + n]);
  if(t < 32) Weet[n * 32 + t] = f2bf(Wee[(size_t)t * 256 + n]);
}

// ---------------- MFMA GEMM:  C[M,N] = A[M,K](bf16) @ Bt[N,K]^T(bf16) ----------------
// EPI 0: +bias -> fp32 (slab, ld=Nld)
// EPI 1: +bias, relu -> bf16
// EPI 2: +bias, relu -> bf16 at permuted row rowmap[r]
// EPI 3: (acc+accv)/denom + skip, relu -> bf16
// EPI 4: (acc+accv)/denom + skip -> fp32
template<int BK, int EPI>
__global__ __launch_bounds__(256) void gemm_k(
    const u16* __restrict__ A, const u16* __restrict__ Bt,
    const float* __restrict__ bias, void* __restrict__ Out,
    const float* __restrict__ accv, const float* __restrict__ denomv,
    const float* __restrict__ skipS, const int* __restrict__ rowmap,
    int Mreal, int Nld, int K)
{
  constexpr int CPR = BK / 8;           // 16B chunks per LDS row
  constexpr int SW  = (BK == 64) ? 7 : 3;
  __shared__ u16 Al[128 * BK];
  __shared__ u16 Bl[128 * BK];
  int tid = threadIdx.x, lane = tid & 63;
  int rowBase = blockIdx.x * 128, colBase = blockIdx.y * 128;
  int wave = tid >> 6, wm = wave >> 1, wn = wave & 1;
  int lr = lane & 15, lk = lane >> 4;
  f32x4 acc[4][4] = {};
  int nkt = K / BK;
  for(int kt = 0; kt < nkt; ++kt){
    __syncthreads();
    for(int ci = tid; ci < 128 * CPR; ci += 256){
      int r = ci / CPR, cb = ci % CPR;
      int d = (r * CPR + (cb ^ (r & SW))) * 8;     // swizzled dest (u16 units)
      *(short8*)&Al[d] = *(const short8*)&A [(size_t)(rowBase + r) * K + kt * BK + cb * 8];
      *(short8*)&Bl[d] = *(const short8*)&Bt[(size_t)(colBase + r) * K + kt * BK + cb * 8];
    }
    __syncthreads();
    #pragma unroll
    for(int kk = 0; kk < BK / 32; ++kk){
      short8 af[4], bfr[4];
      #pragma unroll
      for(int m = 0; m < 4; ++m){
        int r = wm * 64 + m * 16 + lr;
        int byt = r * (BK * 2) + kk * 64 + lk * 16; byt ^= (r & SW) << 4;
        af[m] = *(const short8*)((const char*)Al + byt);
      }
      #pragma unroll
      for(int n = 0; n < 4; ++n){
        int r = wn * 64 + n * 16 + lr;
        int byt = r * (BK * 2) + kk * 64 + lk * 16; byt ^= (r & SW) << 4;
        bfr[n] = *(const short8*)((const char*)Bl + byt);
      }
      #pragma unroll
      for(int m = 0; m < 4; ++m)
        #pragma unroll
        for(int n = 0; n < 4; ++n)
          acc[m][n] = mfma16(af[m], bfr[n], acc[m][n]);
    }
  }
  #pragma unroll
  for(int m = 0; m < 4; ++m){
    #pragma unroll
    for(int n = 0; n < 4; ++n){
      int c = colBase + wn * 64 + n * 16 + lr;
      #pragma unroll
      for(int j = 0; j < 4; ++j){
        int r = rowBase + wm * 64 + m * 16 + lk * 4 + j;
        if(r < Mreal){
          float v = acc[m][n][j];
          if constexpr(EPI == 0){
            v += bias[c]; ((float*)Out)[(size_t)r * Nld + c] = v;
          } else if constexpr(EPI == 1){
            v += bias[c]; v = fmaxf(v, 0.f);
            ((u16*)Out)[(size_t)r * Nld + c] = f2bf(v);
          } else if constexpr(EPI == 2){
            v += bias[c]; v = fmaxf(v, 0.f);
            ((u16*)Out)[(size_t)rowmap[r] * Nld + c] = f2bf(v);
          } else if constexpr(EPI == 3){
            float d = fmaxf(denomv[r], 1e-16f);
            v = (v + accv[(size_t)r * 256 + c]) / d + skipS[(size_t)r * 1280 + 768 + c];
            v = fmaxf(v, 0.f);
            ((u16*)Out)[(size_t)r * Nld + c] = f2bf(v);
          } else {
            float d = fmaxf(denomv[r], 1e-16f);
            v = (v + accv[(size_t)r * 256 + c]) / d + skipS[(size_t)r * 1280 + 768 + c];
            ((float*)Out)[(size_t)r * Nld + c] = v;
          }
        }
      }
    }
  }
}

// ---------------- fused per-node attention pass ----------------
// slab layout per row (ld 1280): q[0:256) k[256:512) v[512:768) skip[768:1024) qWe[1024:1280)
__global__ __launch_bounds__(256) void node_pass_k(
    const float* __restrict__ slab, const u16* __restrict__ efp,
    const int* __restrict__ srcp, const int* __restrict__ offs,
    float* __restrict__ accv, u16* __restrict__ aggef, float* __restrict__ denomv)
{
  int wave = threadIdx.x >> 6, lane = threadIdx.x & 63;
  int n = blockIdx.x * 4 + wave;
  if(n >= NN) return;
  const float* qrow = slab + (size_t)n * 1280;
  float4 q4 = *(const float4*)(qrow + lane * 4);
  float4 e4 = *(const float4*)(qrow + 1024 + lane * 4);
  float av0 = 0, av1 = 0, av2 = 0, av3 = 0;
  float ag0 = 0, ag1 = 0, ag2 = 0, ag3 = 0;
  float den = 0;
  int p0 = offs[n], p1 = offs[n + 1];
  for(int p = p0; p < p1; ++p){
    int s = srcp[p];
    const float* srow = slab + (size_t)s * 1280;
    float4 k4 = *(const float4*)(srow + 256 + lane * 4);
    ushort4 eu = *(const ushort4*)(efp + (size_t)p * 256 + lane * 4);
    float f0 = bf2f(eu.x), f1 = bf2f(eu.y), f2 = bf2f(eu.z), f3 = bf2f(eu.w);
    float part = q4.x * k4.x + q4.y * k4.y + q4.z * k4.z + q4.w * k4.w
               + e4.x * f0 + e4.y * f1 + e4.z * f2 + e4.w * f3;
    #pragma unroll
    for(int o = 32; o >= 1; o >>= 1) part += __shfl_xor(part, o);
    float wgt = expf(part * 0.0625f);            // /sqrt(256)
    den += wgt;
    float4 v4 = *(const float4*)(srow + 512 + lane * 4);
    av0 += wgt * v4.x; av1 += wgt * v4.y; av2 += wgt * v4.z; av3 += wgt * v4.w;
    ag0 += wgt * f0;   ag1 += wgt * f1;   ag2 += wgt * f2;   ag3 += wgt * f3;
  }
  float4 ov; ov.x = av0; ov.y = av1; ov.z = av2; ov.w = av3;
  *(float4*)(accv + (size_t)n * 256 + lane * 4) = ov;
  ushort4 oa; oa.x = f2bf(ag0); oa.y = f2bf(ag1); oa.z = f2bf(ag2); oa.w = f2bf(ag3);
  *(ushort4*)(aggef + (size_t)n * 256 + lane * 4) = oa;
  if(lane == 0) denomv[n] = den;
}

// ---------------- launch ----------------
extern "C" void kernel_launch(void* const* d_in, const int* in_sizes, int n_in,
                              void* d_out, int out_size, void* d_ws, size_t ws_size,
                              hipStream_t stream){
  const float* x     = (const float*)d_in[0];
  const float* eattr = (const float*)d_in[1];
  const int*   src   = (const int*)d_in[2];
  const int*   dst   = (const int*)d_in[3];
  const float* Wee   = (const float*)d_in[4];
  const float* bee   = (const float*)d_in[5];
  const float* Wne   = (const float*)d_in[6];
  const float* bne   = (const float*)d_in[7];
  WPack P;
  for(int l = 0; l < 3; ++l){
    const int b = 8 + l * 9;
    P.Wq[l] = (const float*)d_in[b + 0]; P.bq[l] = (const float*)d_in[b + 1];
    P.Wk[l] = (const float*)d_in[b + 2]; P.bk[l] = (const float*)d_in[b + 3];
    P.Wv[l] = (const float*)d_in[b + 4]; P.bv[l] = (const float*)d_in[b + 5];
    P.We[l] = (const float*)d_in[b + 6];
    P.Ws[l] = (const float*)d_in[b + 7]; P.bs[l] = (const float*)d_in[b + 8];
  }

  char* w = (char*)d_ws; size_t off = 0;
  auto alloc = [&](size_t bytes)->char*{
    char* p = w + off; off = (off + bytes + 255) & ~(size_t)255; return p;
  };
  u16*   Wcat  = (u16*)  alloc((size_t)3 * 1280 * 256 * 2);
  u16*   Wet   = (u16*)  alloc((size_t)3 * 256 * 256 * 2);
  float* biasc = (float*)alloc((size_t)3 * 1280 * 4);
  u16*   Wnet  = (u16*)  alloc((size_t)256 * 128 * 2);
  u16*   Weet  = (u16*)  alloc((size_t)256 * 32 * 2);
  u16*   xbf   = (u16*)  alloc((size_t)MPN * 128 * 2);
  u16*   eabf  = (u16*)  alloc((size_t)MPE * 32 * 2);
  u16*   hbf   = (u16*)  alloc((size_t)MPN * 256 * 2);
  float* slab  = (float*)alloc((size_t)MPN * 1280 * 4);
  u16*   efp   = (u16*)  alloc((size_t)EE * 256 * 2);
  int*   cnt   = (int*)  alloc((size_t)NN * 4);
  int*   offs  = (int*)  alloc((size_t)(NN + 1) * 4);
  int*   cursor= (int*)  alloc((size_t)NN * 4);
  int*   eids  = (int*)  alloc((size_t)EE * 4);
  int*   slotOf= (int*)  alloc((size_t)EE * 4);
  int*   srcp  = (int*)  alloc((size_t)EE * 4);
  float* accv  = (float*)alloc((size_t)NN * 256 * 4);
  u16*   aggef = (u16*)  alloc((size_t)MPN * 256 * 2);
  float* denomv= (float*)alloc((size_t)NN * 4);
  if(off > ws_size) return;   // workspace too small -> visible validation failure

  // CSR build (deterministic: buckets sorted by edge id)
  hipMemsetAsync(cnt, 0, (size_t)NN * 4, stream);
  count_k  <<<(EE + 255) / 256, 256, 0, stream>>>(dst, cnt);
  scan_k   <<<1, 256, 0, stream>>>(cnt, offs, cursor);
  scatter_k<<<(EE + 255) / 256, 256, 0, stream>>>(dst, cursor, eids);
  sortfin_k<<<(NN + 255) / 256, 256, 0, stream>>>(offs, eids, src, slotOf, srcp);

  // input/weight conversion
  conv_bf16_k<<<(MPN * 128 + 255) / 256, 256, 0, stream>>>(x, xbf, NN * 128, MPN * 128);
  conv_bf16_k<<<(MPE * 32 + 255) / 256, 256, 0, stream>>>(eattr, eabf, EE * 32, MPE * 32);
  prepw_k   <<<3 * 1536, 256, 0, stream>>>(P, Wcat, Wet);
  prepbias_k<<<15, 256, 0, stream>>>(P, biasc);
  prepenc_k <<<256, 128, 0, stream>>>(Wne, Wee, Wnet, Weet);

  // node encoder: h = relu(x @ Wne + bne)  -> bf16
  gemm_k<64,1><<<dim3(MPN / 128, 2), 256, 0, stream>>>(
      xbf, Wnet, bne, hbf, nullptr, nullptr, nullptr, nullptr, NN, 256, 128);
  // edge encoder: ef = relu(edge_attr @ Wee + bee) -> bf16, CSR-permuted rows
  gemm_k<32,2><<<dim3(MPE / 128, 2), 256, 0, stream>>>(
      eabf, Weet, bee, efp, nullptr, nullptr, nullptr, slotOf, EE, 256, 32);

  for(int l = 0; l < 3; ++l){
    // fused q|k|v|skip|qWe slab
    gemm_k<64,0><<<dim3(MPN / 128, 10), 256, 0, stream>>>(
        hbf, Wcat + (size_t)l * 1280 * 256, biasc + (size_t)l * 1280, slab,
        nullptr, nullptr, nullptr, nullptr, NN, 1280, 256);
    // per-node attention: scores + exp + weighted sums (no atomics, CSR order)
    node_pass_k<<<NN / 4, 256, 0, stream>>>(slab, efp, srcp, offs, accv, aggef, denomv);
    // out = (accv + aggef@We)/denom + skip  (+relu, bf16 for layers 0,1; fp32 out for layer 2)
    if(l < 2)
      gemm_k<64,3><<<dim3(MPN / 128, 2), 256, 0, stream>>>(
          aggef, Wet + (size_t)l * 256 * 256, nullptr, hbf,
          accv, denomv, slab, nullptr, NN, 256, 256);
    else
      gemm_k<64,4><<<dim3(MPN / 128, 2), 256, 0, stream>>>(
          aggef, Wet + (size_t)l * 256 * 256, nullptr, d_out,
          accv, denomv, slab, nullptr, NN, 256, 256);
  }
}

// Round 2
// 515.719 us; speedup vs baseline: 1.3465x; 1.3465x over previous
//
#include <hip/hip_runtime.h>
#include <cstdint>

typedef unsigned short u16;
typedef __attribute__((ext_vector_type(8))) short short8;
typedef __attribute__((ext_vector_type(8))) __bf16 bf16x8;
typedef __attribute__((ext_vector_type(4))) float f32x4;

#define DEV __device__ __forceinline__

DEV u16 f2bf(float f){
  uint32_t u = __float_as_uint(f);
  u += 0x7fffu + ((u >> 16) & 1u);
  return (u16)(u >> 16);
}
DEV float bf2f(u16 h){ return __uint_as_float(((uint32_t)h) << 16); }

DEV f32x4 mfma16(short8 a, short8 b, f32x4 c){
  return __builtin_amdgcn_mfma_f32_16x16x32_bf16(
      __builtin_bit_cast(bf16x8, a), __builtin_bit_cast(bf16x8, b), c, 0, 0, 0);
}

#define NN 10000
#define EE 160000
#define MPN 10112   /* 79*128  */
#define MPE 160128  /* 1251*128 */

// ---------------- utility kernels ----------------
__global__ void conv_bf16_k(const float* __restrict__ in, u16* __restrict__ out,
                            int n_in, int n_tot){
  int i = blockIdx.x * 256 + threadIdx.x;
  if(i < n_tot) out[i] = (i < n_in) ? f2bf(in[i]) : (u16)0;
}

__global__ void count_k(const int* __restrict__ dst, int* __restrict__ cnt){
  int i = blockIdx.x * 256 + threadIdx.x;
  if(i < EE) atomicAdd(&cnt[dst[i]], 1);
}

// hierarchical scan: local 256-scan -> 1-wave scan of 40 block sums -> apply
__global__ void scan1_k(const int* __restrict__ cnt, int* __restrict__ offs,
                        int* __restrict__ bsum){
  __shared__ int buf[256];
  int b = blockIdx.x, tid = threadIdx.x, i = b * 256 + tid;
  int v = (i < NN) ? cnt[i] : 0;
  buf[tid] = v; __syncthreads();
  for(int d = 1; d < 256; d <<= 1){
    int t = (tid >= d) ? buf[tid - d] : 0;
    __syncthreads();
    buf[tid] += t;
    __syncthreads();
  }
  if(i < NN) offs[i] = buf[tid] - v;      // block-local exclusive
  if(tid == 255) bsum[b] = buf[255];
}

__global__ void scan2_k(const int* __restrict__ bsum, int* __restrict__ bpre){
  int t = threadIdx.x;                     // 1 block, 64 threads
  int v = (t < 40) ? bsum[t] : 0;
  int s = v;
  for(int d = 1; d < 64; d <<= 1){
    int o = __shfl_up(s, d);
    if(t >= d) s += o;
  }
  if(t < 40) bpre[t] = s - v;
}

__global__ void scan3_k(int* __restrict__ offs, const int* __restrict__ bpre,
                        int* __restrict__ cursor){
  int b = blockIdx.x, i = b * 256 + threadIdx.x;
  if(i < NN){ int v = offs[i] + bpre[b]; offs[i] = v; cursor[i] = v; }
  if(i == 0) offs[NN] = EE;
}

__global__ void scatter_k(const int* __restrict__ dst, int* __restrict__ cursor,
                          int* __restrict__ eids){
  int i = blockIdx.x * 256 + threadIdx.x;
  if(i < EE){ int p = atomicAdd(&cursor[dst[i]], 1); eids[p] = i; }
}

// deterministic rank: slot(e) = offs[dst] + #{e' in bucket : e' < e}
// (bucket CONTENTS are deterministic; order from atomics is irrelevant here)
__global__ void rank_k(const int* __restrict__ dst, const int* __restrict__ src,
                       const int* __restrict__ offs, const int* __restrict__ eids,
                       int* __restrict__ slotOf, int* __restrict__ srcp){
  int e = blockIdx.x * 256 + threadIdx.x;
  if(e >= EE) return;
  int n = dst[e];
  int p0 = offs[n], p1 = offs[n + 1];
  int rk = 0;
  for(int p = p0; p < p1; ++p) rk += (eids[p] < e) ? 1 : 0;
  int slot = p0 + rk;
  slotOf[e] = slot;
  srcp[slot] = src[e];
}

// ---------------- weight prep ----------------
struct WPack {
  const float* Wq[3]; const float* Wk[3]; const float* Wv[3];
  const float* Ws[3]; const float* We[3];
  const float* bq[3]; const float* bk[3]; const float* bv[3]; const float* bs[3];
};

// Wcat layout per layer: rows [0,256) Wq^T, [256,512) Wk^T, [512,768) Wv^T,
// [768,1024) Ws^T, [1024,1280) (Wq@We^T)^T (filled by MFMA GEMM, EPI 5).
__global__ __launch_bounds__(256) void prepw_k(WPack P, u16* __restrict__ Wcat,
                                               u16* __restrict__ Wet){
  int b = blockIdx.x; int l = b / 1280, r = b % 1280; int k = threadIdx.x;
  if(r < 1024){
    int sec = r >> 8, n = r & 255; float v;
    if(sec == 0)      v = P.Wq[l][k * 256 + n];
    else if(sec == 1) v = P.Wk[l][k * 256 + n];
    else if(sec == 2) v = P.Wv[l][k * 256 + n];
    else              v = P.Ws[l][k * 256 + n];
    Wcat[((size_t)l * 1280 + r) * 256 + k] = f2bf(v);
  } else {
    int n = r - 1024;
    Wet[((size_t)l * 256 + n) * 256 + k] = f2bf(P.We[l][k * 256 + n]);
  }
}

// bf16 copies of Wq, We in original [in][out] layout, for the weight GEMM
__global__ void convW_k(WPack P, u16* __restrict__ WqBF, u16* __restrict__ WeBF){
  int b = blockIdx.x; int l = b >> 9, rr = b & 511; int t = threadIdx.x;
  if(rr < 256) WqBF[((size_t)l * 256 + rr) * 256 + t] = f2bf(P.Wq[l][rr * 256 + t]);
  else         WeBF[((size_t)l * 256 + (rr - 256)) * 256 + t] = f2bf(P.We[l][(rr - 256) * 256 + t]);
}

__global__ void prepbias_k(WPack P, float* __restrict__ bias_cat){
  int b = blockIdx.x; int l = b / 5, seg = b % 5; int t = threadIdx.x;
  float v;
  if(seg == 0)      v = P.bq[l][t];
  else if(seg == 1) v = P.bk[l][t];
  else if(seg == 2) v = P.bv[l][t];
  else if(seg == 3) v = P.bs[l][t];
  else{
    const float* we = P.We[l] + (size_t)t * 256; const float* bq = P.bq[l];
    float s = 0.f;
    for(int c = 0; c < 256; ++c) s += bq[c] * we[c];
    v = s;
  }
  bias_cat[(size_t)l * 1280 + seg * 256 + t] = v;
}

__global__ void prepenc_k(const float* __restrict__ Wne, const float* __restrict__ Wee,
                          u16* __restrict__ Wnet, u16* __restrict__ Weet){
  int n = blockIdx.x, t = threadIdx.x;   // grid 256, block 128
  Wnet[n * 128 + t] = f2bf(Wne[(size_t)t * 256 + n]);
  if(t < 32) Weet[n * 32 + t] = f2bf(Wee[(size_t)t * 256 + n]);
}

// ---------------- MFMA GEMM:  C[M,N] = A[M,K](bf16) @ Bt[N,K]^T(bf16) ----------------
// EPI 0: +bias -> fp32 (slab, ld=Nld); cols [256,768) also -> bf16 kvout[r][c-256]
// EPI 1: +bias, relu -> bf16
// EPI 2: +bias, relu -> bf16 at permuted row rowmap[r]
// EPI 3: (acc+accv)/denom + skip, relu -> bf16
// EPI 4: (acc+accv)/denom + skip -> fp32
// EPI 5: plain -> bf16 (weight-prep GEMM)
template<int BK, int EPI>
__global__ __launch_bounds__(256) void gemm_k(
    const u16* __restrict__ A, const u16* __restrict__ Bt,
    const float* __restrict__ bias, void* __restrict__ Out,
    const float* __restrict__ accv, const float* __restrict__ denomv,
    const float* __restrict__ skipS, const int* __restrict__ rowmap,
    u16* __restrict__ kvout, int Mreal, int Nld, int K)
{
  constexpr int CPR = BK / 8;           // 16B chunks per LDS row
  constexpr int SW  = (BK == 64) ? 7 : 3;
  __shared__ u16 Al[128 * BK];
  __shared__ u16 Bl[128 * BK];
  int tid = threadIdx.x, lane = tid & 63;
  int rowBase = blockIdx.x * 128, colBase = blockIdx.y * 128;
  int wave = tid >> 6, wm = wave >> 1, wn = wave & 1;
  int lr = lane & 15, lk = lane >> 4;
  f32x4 acc[4][4] = {};
  int nkt = K / BK;
  for(int kt = 0; kt < nkt; ++kt){
    __syncthreads();
    for(int ci = tid; ci < 128 * CPR; ci += 256){
      int r = ci / CPR, cb = ci % CPR;
      int d = (r * CPR + (cb ^ (r & SW))) * 8;     // swizzled dest (u16 units)
      *(short8*)&Al[d] = *(const short8*)&A [(size_t)(rowBase + r) * K + kt * BK + cb * 8];
      *(short8*)&Bl[d] = *(const short8*)&Bt[(size_t)(colBase + r) * K + kt * BK + cb * 8];
    }
    __syncthreads();
    #pragma unroll
    for(int kk = 0; kk < BK / 32; ++kk){
      short8 af[4], bfr[4];
      #pragma unroll
      for(int m = 0; m < 4; ++m){
        int r = wm * 64 + m * 16 + lr;
        int byt = r * (BK * 2) + kk * 64 + lk * 16; byt ^= (r & SW) << 4;
        af[m] = *(const short8*)((const char*)Al + byt);
      }
      #pragma unroll
      for(int n = 0; n < 4; ++n){
        int r = wn * 64 + n * 16 + lr;
        int byt = r * (BK * 2) + kk * 64 + lk * 16; byt ^= (r & SW) << 4;
        bfr[n] = *(const short8*)((const char*)Bl + byt);
      }
      #pragma unroll
      for(int m = 0; m < 4; ++m)
        #pragma unroll
        for(int n = 0; n < 4; ++n)
          acc[m][n] = mfma16(af[m], bfr[n], acc[m][n]);
    }
  }
  #pragma unroll
  for(int m = 0; m < 4; ++m){
    #pragma unroll
    for(int n = 0; n < 4; ++n){
      int c = colBase + wn * 64 + n * 16 + lr;
      #pragma unroll
      for(int j = 0; j < 4; ++j){
        int r = rowBase + wm * 64 + m * 16 + lk * 4 + j;
        if(r < Mreal){
          float v = acc[m][n][j];
          if constexpr(EPI == 0){
            v += bias[c]; ((float*)Out)[(size_t)r * Nld + c] = v;
            if(c >= 256 && c < 768) kvout[(size_t)r * 512 + (c - 256)] = f2bf(v);
          } else if constexpr(EPI == 1){
            v += bias[c]; v = fmaxf(v, 0.f);
            ((u16*)Out)[(size_t)r * Nld + c] = f2bf(v);
          } else if constexpr(EPI == 2){
            v += bias[c]; v = fmaxf(v, 0.f);
            ((u16*)Out)[(size_t)rowmap[r] * Nld + c] = f2bf(v);
          } else if constexpr(EPI == 3){
            float d = fmaxf(denomv[r], 1e-16f);
            v = (v + accv[(size_t)r * 256 + c]) / d + skipS[(size_t)r * 1280 + 768 + c];
            v = fmaxf(v, 0.f);
            ((u16*)Out)[(size_t)r * Nld + c] = f2bf(v);
          } else if constexpr(EPI == 4){
            float d = fmaxf(denomv[r], 1e-16f);
            v = (v + accv[(size_t)r * 256 + c]) / d + skipS[(size_t)r * 1280 + 768 + c];
            ((float*)Out)[(size_t)r * Nld + c] = v;
          } else {
            ((u16*)Out)[(size_t)r * Nld + c] = f2bf(v);
          }
        }
      }
    }
  }
}

// ---------------- fused per-node attention pass ----------------
// slab layout per row (ld 1280): q[0:256) k[256:512) v[512:768) skip[768:1024) qWe[1024:1280)
// kvbf row (ld 512 bf16): k[0:256) v[256:512)
__global__ __launch_bounds__(256) void node_pass_k(
    const float* __restrict__ slab, const u16* __restrict__ efp,
    const u16* __restrict__ kvbf,
    const int* __restrict__ srcp, const int* __restrict__ offs,
    float* __restrict__ accv, u16* __restrict__ aggef, float* __restrict__ denomv)
{
  int wave = threadIdx.x >> 6, lane = threadIdx.x & 63;
  int n = blockIdx.x * 4 + wave;
  if(n >= NN) return;
  const float* qrow = slab + (size_t)n * 1280;
  float4 q4 = *(const float4*)(qrow + lane * 4);
  float4 e4 = *(const float4*)(qrow + 1024 + lane * 4);
  float av0 = 0, av1 = 0, av2 = 0, av3 = 0;
  float ag0 = 0, ag1 = 0, ag2 = 0, ag3 = 0;
  float den = 0;
  int p0 = offs[n], p1 = offs[n + 1];
  for(int p = p0; p < p1; ++p){
    int s = srcp[p];
    const u16* kv = kvbf + (size_t)s * 512;
    ushort4 ku = *(const ushort4*)(kv + lane * 4);
    ushort4 vu = *(const ushort4*)(kv + 256 + lane * 4);
    ushort4 eu = *(const ushort4*)(efp + (size_t)p * 256 + lane * 4);
    float f0 = bf2f(eu.x), f1 = bf2f(eu.y), f2 = bf2f(eu.z), f3 = bf2f(eu.w);
    float part = q4.x * bf2f(ku.x) + q4.y * bf2f(ku.y)
               + q4.z * bf2f(ku.z) + q4.w * bf2f(ku.w)
               + e4.x * f0 + e4.y * f1 + e4.z * f2 + e4.w * f3;
    #pragma unroll
    for(int o = 32; o >= 1; o >>= 1) part += __shfl_xor(part, o);
    float wgt = __expf(part * 0.0625f);            // /sqrt(256)
    den += wgt;
    av0 += wgt * bf2f(vu.x); av1 += wgt * bf2f(vu.y);
    av2 += wgt * bf2f(vu.z); av3 += wgt * bf2f(vu.w);
    ag0 += wgt * f0;   ag1 += wgt * f1;   ag2 += wgt * f2;   ag3 += wgt * f3;
  }
  float4 ov; ov.x = av0; ov.y = av1; ov.z = av2; ov.w = av3;
  *(float4*)(accv + (size_t)n * 256 + lane * 4) = ov;
  ushort4 oa; oa.x = f2bf(ag0); oa.y = f2bf(ag1); oa.z = f2bf(ag2); oa.w = f2bf(ag3);
  *(ushort4*)(aggef + (size_t)n * 256 + lane * 4) = oa;
  if(lane == 0) denomv[n] = den;
}

// ---------------- launch ----------------
extern "C" void kernel_launch(void* const* d_in, const int* in_sizes, int n_in,
                              void* d_out, int out_size, void* d_ws, size_t ws_size,
                              hipStream_t stream){
  const float* x     = (const float*)d_in[0];
  const float* eattr = (const float*)d_in[1];
  const int*   src   = (const int*)d_in[2];
  const int*   dst   = (const int*)d_in[3];
  const float* Wee   = (const float*)d_in[4];
  const float* bee   = (const float*)d_in[5];
  const float* Wne   = (const float*)d_in[6];
  const float* bne   = (const float*)d_in[7];
  WPack P;
  for(int l = 0; l < 3; ++l){
    const int b = 8 + l * 9;
    P.Wq[l] = (const float*)d_in[b + 0]; P.bq[l] = (const float*)d_in[b + 1];
    P.Wk[l] = (const float*)d_in[b + 2]; P.bk[l] = (const float*)d_in[b + 3];
    P.Wv[l] = (const float*)d_in[b + 4]; P.bv[l] = (const float*)d_in[b + 5];
    P.We[l] = (const float*)d_in[b + 6];
    P.Ws[l] = (const float*)d_in[b + 7]; P.bs[l] = (const float*)d_in[b + 8];
  }

  char* w = (char*)d_ws; size_t off = 0;
  auto alloc = [&](size_t bytes)->char*{
    char* p = w + off; off = (off + bytes + 255) & ~(size_t)255; return p;
  };
  u16*   Wcat  = (u16*)  alloc((size_t)3 * 1280 * 256 * 2);
  u16*   Wet   = (u16*)  alloc((size_t)3 * 256 * 256 * 2);
  u16*   WqBF  = (u16*)  alloc((size_t)3 * 256 * 256 * 2);
  u16*   WeBF  = (u16*)  alloc((size_t)3 * 256 * 256 * 2);
  float* biasc = (float*)alloc((size_t)3 * 1280 * 4);
  u16*   Wnet  = (u16*)  alloc((size_t)256 * 128 * 2);
  u16*   Weet  = (u16*)  alloc((size_t)256 * 32 * 2);
  u16*   xbf   = (u16*)  alloc((size_t)MPN * 128 * 2);
  u16*   eabf  = (u16*)  alloc((size_t)MPE * 32 * 2);
  u16*   hbf   = (u16*)  alloc((size_t)MPN * 256 * 2);
  float* slab  = (float*)alloc((size_t)MPN * 1280 * 4);
  u16*   kvbf  = (u16*)  alloc((size_t)MPN * 512 * 2);
  u16*   efp   = (u16*)  alloc((size_t)EE * 256 * 2);
  int*   cnt   = (int*)  alloc((size_t)NN * 4);
  int*   offs  = (int*)  alloc((size_t)(NN + 1) * 4);
  int*   cursor= (int*)  alloc((size_t)NN * 4);
  int*   bsum  = (int*)  alloc((size_t)64 * 4);
  int*   bpre  = (int*)  alloc((size_t)64 * 4);
  int*   eids  = (int*)  alloc((size_t)EE * 4);
  int*   slotOf= (int*)  alloc((size_t)EE * 4);
  int*   srcp  = (int*)  alloc((size_t)EE * 4);
  float* accv  = (float*)alloc((size_t)NN * 256 * 4);
  u16*   aggef = (u16*)  alloc((size_t)MPN * 256 * 2);
  float* denomv= (float*)alloc((size_t)NN * 4);
  if(off > ws_size) return;   // workspace too small -> visible validation failure

  // CSR build (deterministic: rank-by-edge-id, no sort)
  hipMemsetAsync(cnt, 0, (size_t)NN * 4, stream);
  count_k <<<(EE + 255) / 256, 256, 0, stream>>>(dst, cnt);
  scan1_k <<<40, 256, 0, stream>>>(cnt, offs, bsum);
  scan2_k <<<1, 64, 0, stream>>>(bsum, bpre);
  scan3_k <<<40, 256, 0, stream>>>(offs, bpre, cursor);
  scatter_k<<<(EE + 255) / 256, 256, 0, stream>>>(dst, cursor, eids);
  rank_k  <<<(EE + 255) / 256, 256, 0, stream>>>(dst, src, offs, eids, slotOf, srcp);

  // input/weight conversion
  conv_bf16_k<<<(MPN * 128 + 255) / 256, 256, 0, stream>>>(x, xbf, NN * 128, MPN * 128);
  conv_bf16_k<<<(MPE * 32 + 255) / 256, 256, 0, stream>>>(eattr, eabf, EE * 32, MPE * 32);
  prepw_k   <<<3 * 1280, 256, 0, stream>>>(P, Wcat, Wet);
  convW_k   <<<3 * 512, 256, 0, stream>>>(P, WqBF, WeBF);
  prepbias_k<<<15, 256, 0, stream>>>(P, biasc);
  prepenc_k <<<256, 128, 0, stream>>>(Wne, Wee, Wnet, Weet);

  // qWe weight per layer: Wcat sec4 row c, elem k = sum_j We[c][j]*Wq[k][j]
  for(int l = 0; l < 3; ++l)
    gemm_k<64,5><<<dim3(2, 2), 256, 0, stream>>>(
        WeBF + (size_t)l * 256 * 256, WqBF + (size_t)l * 256 * 256, nullptr,
        Wcat + ((size_t)l * 1280 + 1024) * 256,
        nullptr, nullptr, nullptr, nullptr, nullptr, 256, 256, 256);

  // node encoder: h = relu(x @ Wne + bne)  -> bf16
  gemm_k<64,1><<<dim3(MPN / 128, 2), 256, 0, stream>>>(
      xbf, Wnet, bne, hbf, nullptr, nullptr, nullptr, nullptr, nullptr, NN, 256, 128);
  // edge encoder: ef = relu(edge_attr @ Wee + bee) -> bf16, CSR-permuted rows
  gemm_k<32,2><<<dim3(MPE / 128, 2), 256, 0, stream>>>(
      eabf, Weet, bee, efp, nullptr, nullptr, nullptr, slotOf, nullptr, EE, 256, 32);

  for(int l = 0; l < 3; ++l){
    // fused q|k|v|skip|qWe slab (+ bf16 k|v side copy)
    gemm_k<64,0><<<dim3(MPN / 128, 10), 256, 0, stream>>>(
        hbf, Wcat + (size_t)l * 1280 * 256, biasc + (size_t)l * 1280, slab,
        nullptr, nullptr, nullptr, nullptr, kvbf, NN, 1280, 256);
    // per-node attention: scores + exp + weighted sums (no atomics, CSR order)
    node_pass_k<<<NN / 4, 256, 0, stream>>>(slab, efp, kvbf, srcp, offs, accv, aggef, denomv);
    // out = (accv + aggef@We)/denom + skip  (+relu, bf16 for layers 0,1; fp32 out for layer 2)
    if(l < 2)
      gemm_k<64,3><<<dim3(MPN / 128, 2), 256, 0, stream>>>(
          aggef, Wet + (size_t)l * 256 * 256, nullptr, hbf,
          accv, denomv, slab, nullptr, nullptr, NN, 256, 256);
    else
      gemm_k<64,4><<<dim3(MPN / 128, 2), 256, 0, stream>>>(
          aggef, Wet + (size_t)l * 256 * 256, nullptr, d_out,
          accv, denomv, slab, nullptr, nullptr, NN, 256, 256);
  }
}

// Round 3
// 499.088 us; speedup vs baseline: 1.3913x; 1.0333x over previous
//
#include <hip/hip_runtime.h>
#include <cstdint>

typedef unsigned short u16;
typedef __attribute__((ext_vector_type(8))) short short8;
typedef __attribute__((ext_vector_type(8))) __bf16 bf16x8;
typedef __attribute__((ext_vector_type(4))) float f32x4;

#define DEV __device__ __forceinline__

DEV u16 f2bf(float f){
  uint32_t u = __float_as_uint(f);
  u += 0x7fffu + ((u >> 16) & 1u);
  return (u16)(u >> 16);
}
DEV float bf2f(u16 h){ return __uint_as_float(((uint32_t)h) << 16); }

DEV f32x4 mfma16(short8 a, short8 b, f32x4 c){
  return __builtin_amdgcn_mfma_f32_16x16x32_bf16(
      __builtin_bit_cast(bf16x8, a), __builtin_bit_cast(bf16x8, b), c, 0, 0, 0);
}

#define NN 10000
#define EE 160000
#define MPN 10112   /* 79*128  */
#define MPE 160128  /* 1251*128 */

// ---------------- utility kernels ----------------
__global__ void conv_bf16_k(const float* __restrict__ in, u16* __restrict__ out,
                            int n_in, int n_tot){
  int i = blockIdx.x * 256 + threadIdx.x;
  if(i < n_tot) out[i] = (i < n_in) ? f2bf(in[i]) : (u16)0;
}

__global__ void count_k(const int* __restrict__ dst, int* __restrict__ cnt){
  int i = blockIdx.x * 256 + threadIdx.x;
  if(i < EE) atomicAdd(&cnt[dst[i]], 1);
}

// hierarchical scan: local 256-scan -> 1-wave scan of 40 block sums -> apply
__global__ void scan1_k(const int* __restrict__ cnt, int* __restrict__ offs,
                        int* __restrict__ bsum){
  __shared__ int buf[256];
  int b = blockIdx.x, tid = threadIdx.x, i = b * 256 + tid;
  int v = (i < NN) ? cnt[i] : 0;
  buf[tid] = v; __syncthreads();
  for(int d = 1; d < 256; d <<= 1){
    int t = (tid >= d) ? buf[tid - d] : 0;
    __syncthreads();
    buf[tid] += t;
    __syncthreads();
  }
  if(i < NN) offs[i] = buf[tid] - v;      // block-local exclusive
  if(tid == 255) bsum[b] = buf[255];
}

__global__ void scan2_k(const int* __restrict__ bsum, int* __restrict__ bpre){
  int t = threadIdx.x;                     // 1 block, 64 threads
  int v = (t < 40) ? bsum[t] : 0;
  int s = v;
  for(int d = 1; d < 64; d <<= 1){
    int o = __shfl_up(s, d);
    if(t >= d) s += o;
  }
  if(t < 40) bpre[t] = s - v;
}

__global__ void scan3_k(int* __restrict__ offs, const int* __restrict__ bpre,
                        int* __restrict__ cursor){
  int b = blockIdx.x, i = b * 256 + threadIdx.x;
  if(i < NN){ int v = offs[i] + bpre[b]; offs[i] = v; cursor[i] = v; }
  if(i == 0) offs[NN] = EE;
}

__global__ void scatter_k(const int* __restrict__ dst, int* __restrict__ cursor,
                          int* __restrict__ eids){
  int i = blockIdx.x * 256 + threadIdx.x;
  if(i < EE){ int p = atomicAdd(&cursor[dst[i]], 1); eids[p] = i; }
}

// deterministic rank: slot(e) = offs[dst] + #{e' in bucket : e' < e}
// writes the INVERSE map eidp[slot] = e  (A-side gather for the edge GEMM)
__global__ void rank_k(const int* __restrict__ dst, const int* __restrict__ src,
                       const int* __restrict__ offs, const int* __restrict__ eids,
                       int* __restrict__ eidp, int* __restrict__ srcp){
  int e = blockIdx.x * 256 + threadIdx.x;
  if(e >= MPE) return;
  if(e >= EE){ eidp[e] = e; return; }      // pad slots -> zero rows of eabf
  int n = dst[e];
  int p0 = offs[n], p1 = offs[n + 1];
  int rk = 0;
  for(int p = p0; p < p1; ++p) rk += (eids[p] < e) ? 1 : 0;
  int slot = p0 + rk;
  eidp[slot] = e;
  srcp[slot] = src[e];
}

// ---------------- weight prep ----------------
struct WPack {
  const float* Wq[3]; const float* Wk[3]; const float* Wv[3];
  const float* Ws[3]; const float* We[3];
  const float* bq[3]; const float* bk[3]; const float* bv[3]; const float* bs[3];
};

// Wcat rows per layer: [0,256) Wq^T | [256,512) Ws^T | [512,768) qWe (GEMM EPI5)
//                      | [768,1024) Wk^T | [1024,1280) Wv^T
__global__ __launch_bounds__(256) void prepw_k(WPack P, u16* __restrict__ Wcat,
                                               u16* __restrict__ Wet){
  int b = blockIdx.x; int l = b / 1280, r = b % 1280; int k = threadIdx.x;
  float v;
  if(r < 256)       v = P.Wq[l][k * 256 + r];
  else if(r < 512)  v = P.Ws[l][k * 256 + (r - 256)];
  else if(r < 768){ Wet[((size_t)l * 256 + (r - 512)) * 256 + k] =
                      f2bf(P.We[l][k * 256 + (r - 512)]); return; }
  else if(r < 1024) v = P.Wk[l][k * 256 + (r - 768)];
  else              v = P.Wv[l][k * 256 + (r - 1024)];
  Wcat[((size_t)l * 1280 + r) * 256 + k] = f2bf(v);
}

// bf16 copies of Wq, We in original [in][out] layout, for the weight GEMM
__global__ void convW_k(WPack P, u16* __restrict__ WqBF, u16* __restrict__ WeBF){
  int b = blockIdx.x; int l = b >> 9, rr = b & 511; int t = threadIdx.x;
  if(rr < 256) WqBF[((size_t)l * 256 + rr) * 256 + t] = f2bf(P.Wq[l][rr * 256 + t]);
  else         WeBF[((size_t)l * 256 + (rr - 256)) * 256 + t] = f2bf(P.We[l][(rr - 256) * 256 + t]);
}

// bias rows per layer (ld 1280): bq | bs | bqWe | bk | bv
__global__ void prepbias_k(WPack P, float* __restrict__ bias_cat){
  int b = blockIdx.x; int l = b / 5, seg = b % 5; int t = threadIdx.x;
  float v;
  if(seg == 0)      v = P.bq[l][t];
  else if(seg == 1) v = P.bs[l][t];
  else if(seg == 2){
    const float* we = P.We[l] + (size_t)t * 256; const float* bq = P.bq[l];
    float s = 0.f;
    for(int c = 0; c < 256; ++c) s += bq[c] * we[c];
    v = s;
  }
  else if(seg == 3) v = P.bk[l][t];
  else              v = P.bv[l][t];
  bias_cat[(size_t)l * 1280 + seg * 256 + t] = v;
}

__global__ void prepenc_k(const float* __restrict__ Wne, const float* __restrict__ Wee,
                          u16* __restrict__ Wnet, u16* __restrict__ Weet){
  int n = blockIdx.x, t = threadIdx.x;   // grid 256, block 128
  Wnet[n * 128 + t] = f2bf(Wne[(size_t)t * 256 + n]);
  if(t < 32) Weet[n * 32 + t] = f2bf(Wee[(size_t)t * 256 + n]);
}

// ---------------- MFMA GEMM:  C[M,N] = A[M,K](bf16) @ Bt[N,K]^T(bf16) ----------------
// AG: gather A rows through rowmap.
// EPI 0: +bias; c<768 -> fp32 slab (ld Nld); c>=768 -> bf16 kvout[r][c-768]
// EPI 1: +bias, relu -> bf16
// EPI 3: acc + accv + skip, relu -> bf16   (accv pre-divided by denom)
// EPI 4: acc + accv + skip -> fp32
// EPI 5: plain -> bf16 (weight-prep GEMM)
template<int BK, int EPI, int AG = 0>
__global__ __launch_bounds__(256) void gemm_k(
    const u16* __restrict__ A, const u16* __restrict__ Bt,
    const float* __restrict__ bias, void* __restrict__ Out,
    const float* __restrict__ accv, const float* __restrict__ skipS,
    const int* __restrict__ rowmap, u16* __restrict__ kvout,
    int Mreal, int Nld, int K)
{
  constexpr int CPR = BK / 8;           // 16B chunks per LDS row
  constexpr int SW  = (BK == 64) ? 7 : 3;
  __shared__ u16 Al[128 * BK];
  __shared__ u16 Bl[128 * BK];
  int tid = threadIdx.x, lane = tid & 63;
  int rowBase = blockIdx.x * 128, colBase = blockIdx.y * 128;
  int wave = tid >> 6, wm = wave >> 1, wn = wave & 1;
  int lr = lane & 15, lk = lane >> 4;
  f32x4 acc[4][4] = {};
  int nkt = K / BK;
  for(int kt = 0; kt < nkt; ++kt){
    __syncthreads();
    for(int ci = tid; ci < 128 * CPR; ci += 256){
      int r = ci / CPR, cb = ci % CPR;
      int ar = AG ? rowmap[rowBase + r] : (rowBase + r);
      int d = (r * CPR + (cb ^ (r & SW))) * 8;     // swizzled dest (u16 units)
      *(short8*)&Al[d] = *(const short8*)&A [(size_t)ar * K + kt * BK + cb * 8];
      *(short8*)&Bl[d] = *(const short8*)&Bt[(size_t)(colBase + r) * K + kt * BK + cb * 8];
    }
    __syncthreads();
    #pragma unroll
    for(int kk = 0; kk < BK / 32; ++kk){
      short8 af[4], bfr[4];
      #pragma unroll
      for(int m = 0; m < 4; ++m){
        int r = wm * 64 + m * 16 + lr;
        int byt = r * (BK * 2) + kk * 64 + lk * 16; byt ^= (r & SW) << 4;
        af[m] = *(const short8*)((const char*)Al + byt);
      }
      #pragma unroll
      for(int n = 0; n < 4; ++n){
        int r = wn * 64 + n * 16 + lr;
        int byt = r * (BK * 2) + kk * 64 + lk * 16; byt ^= (r & SW) << 4;
        bfr[n] = *(const short8*)((const char*)Bl + byt);
      }
      #pragma unroll
      for(int m = 0; m < 4; ++m)
        #pragma unroll
        for(int n = 0; n < 4; ++n)
          acc[m][n] = mfma16(af[m], bfr[n], acc[m][n]);
    }
  }
  #pragma unroll
  for(int m = 0; m < 4; ++m){
    #pragma unroll
    for(int n = 0; n < 4; ++n){
      int c = colBase + wn * 64 + n * 16 + lr;
      #pragma unroll
      for(int j = 0; j < 4; ++j){
        int r = rowBase + wm * 64 + m * 16 + lk * 4 + j;
        if(r < Mreal){
          float v = acc[m][n][j];
          if constexpr(EPI == 0){
            v += bias[c];
            if(c < 768) ((float*)Out)[(size_t)r * Nld + c] = v;
            else        kvout[(size_t)r * 512 + (c - 768)] = f2bf(v);
          } else if constexpr(EPI == 1){
            v += bias[c]; v = fmaxf(v, 0.f);
            ((u16*)Out)[(size_t)r * Nld + c] = f2bf(v);
          } else if constexpr(EPI == 3){
            v = v + accv[(size_t)r * 256 + c] + skipS[(size_t)r * 768 + 256 + c];
            v = fmaxf(v, 0.f);
            ((u16*)Out)[(size_t)r * Nld + c] = f2bf(v);
          } else if constexpr(EPI == 4){
            v = v + accv[(size_t)r * 256 + c] + skipS[(size_t)r * 768 + 256 + c];
            ((float*)Out)[(size_t)r * Nld + c] = v;
          } else {
            ((u16*)Out)[(size_t)r * Nld + c] = f2bf(v);
          }
        }
      }
    }
  }
}

// ---------------- fused per-node attention pass ----------------
// slab row (ld 768 fp32): q[0:256) skip[256:512) qWe[512:768)
// kvbf row (ld 512 bf16): k[0:256) v[256:512)
// 4 edges in flight per wave: 16 lanes per edge, 16 dims per lane.
__global__ __launch_bounds__(256) void node_pass_k(
    const float* __restrict__ slab, const u16* __restrict__ efp,
    const u16* __restrict__ kvbf,
    const int* __restrict__ srcp, const int* __restrict__ offs,
    float* __restrict__ accv, u16* __restrict__ aggef)
{
  int wave = threadIdx.x >> 6, lane = threadIdx.x & 63;
  int n = blockIdx.x * 4 + wave;
  if(n >= NN) return;
  int li = lane & 15, eg = lane >> 4;
  const float* qrow = slab + (size_t)n * 768 + li * 16;
  float q[16], e[16];
  #pragma unroll
  for(int t = 0; t < 4; ++t){
    float4 a = *(const float4*)(qrow + t * 4);
    float4 b = *(const float4*)(qrow + 512 + t * 4);
    q[t*4+0] = a.x; q[t*4+1] = a.y; q[t*4+2] = a.z; q[t*4+3] = a.w;
    e[t*4+0] = b.x; e[t*4+1] = b.y; e[t*4+2] = b.z; e[t*4+3] = b.w;
  }
  float av[16], ag[16];
  #pragma unroll
  for(int d = 0; d < 16; ++d){ av[d] = 0.f; ag[d] = 0.f; }
  float den = 0.f;
  int p0 = offs[n], p1 = offs[n + 1];
  for(int p = p0 + eg; p < p1; p += 4){
    int s = srcp[p];
    const u16* kvp = kvbf + (size_t)s * 512 + li * 16;
    const u16* epp = efp + (size_t)p * 256 + li * 16;
    short8 kA = *(const short8*)(kvp);
    short8 kB = *(const short8*)(kvp + 8);
    short8 vA = *(const short8*)(kvp + 256);
    short8 vB = *(const short8*)(kvp + 264);
    short8 fA = *(const short8*)(epp);
    short8 fB = *(const short8*)(epp + 8);
    float part = 0.f;
    #pragma unroll
    for(int d = 0; d < 8; ++d){
      part += q[d]   * bf2f((u16)kA[d]) + e[d]   * bf2f((u16)fA[d]);
      part += q[8+d] * bf2f((u16)kB[d]) + e[8+d] * bf2f((u16)fB[d]);
    }
    part += __shfl_xor(part, 1);
    part += __shfl_xor(part, 2);
    part += __shfl_xor(part, 4);
    part += __shfl_xor(part, 8);
    float wgt = __expf(part * 0.0625f);            // /sqrt(256)
    den += wgt;
    #pragma unroll
    for(int d = 0; d < 8; ++d){
      av[d]   += wgt * bf2f((u16)vA[d]);
      av[8+d] += wgt * bf2f((u16)vB[d]);
      ag[d]   += wgt * bf2f((u16)fA[d]);
      ag[8+d] += wgt * bf2f((u16)fB[d]);
    }
  }
  // combine the 4 edge-groups
  #pragma unroll
  for(int d = 0; d < 16; ++d){
    av[d] += __shfl_xor(av[d], 16); av[d] += __shfl_xor(av[d], 32);
    ag[d] += __shfl_xor(ag[d], 16); ag[d] += __shfl_xor(ag[d], 32);
  }
  den += __shfl_xor(den, 16); den += __shfl_xor(den, 32);
  float rden = 1.f / fmaxf(den, 1e-16f);          // pre-divide (linear in We)
  if(eg == 0){
    float* ao = accv + (size_t)n * 256 + li * 16;
    #pragma unroll
    for(int t = 0; t < 4; ++t){
      float4 o;
      o.x = av[t*4+0] * rden; o.y = av[t*4+1] * rden;
      o.z = av[t*4+2] * rden; o.w = av[t*4+3] * rden;
      *(float4*)(ao + t * 4) = o;
    }
  } else if(eg == 1){
    u16* go = aggef + (size_t)n * 256 + li * 16;
    #pragma unroll
    for(int t = 0; t < 2; ++t){
      short8 o;
      #pragma unroll
      for(int d = 0; d < 8; ++d) o[d] = (short)f2bf(ag[t*8+d] * rden);
      *(short8*)(go + t * 8) = o;
    }
  }
}

// ---------------- launch ----------------
extern "C" void kernel_launch(void* const* d_in, const int* in_sizes, int n_in,
                              void* d_out, int out_size, void* d_ws, size_t ws_size,
                              hipStream_t stream){
  const float* x     = (const float*)d_in[0];
  const float* eattr = (const float*)d_in[1];
  const int*   src   = (const int*)d_in[2];
  const int*   dst   = (const int*)d_in[3];
  const float* Wee   = (const float*)d_in[4];
  const float* bee   = (const float*)d_in[5];
  const float* Wne   = (const float*)d_in[6];
  const float* bne   = (const float*)d_in[7];
  WPack P;
  for(int l = 0; l < 3; ++l){
    const int b = 8 + l * 9;
    P.Wq[l] = (const float*)d_in[b + 0]; P.bq[l] = (const float*)d_in[b + 1];
    P.Wk[l] = (const float*)d_in[b + 2]; P.bk[l] = (const float*)d_in[b + 3];
    P.Wv[l] = (const float*)d_in[b + 4]; P.bv[l] = (const float*)d_in[b + 5];
    P.We[l] = (const float*)d_in[b + 6];
    P.Ws[l] = (const float*)d_in[b + 7]; P.bs[l] = (const float*)d_in[b + 8];
  }

  char* w = (char*)d_ws; size_t off = 0;
  auto alloc = [&](size_t bytes)->char*{
    char* p = w + off; off = (off + bytes + 255) & ~(size_t)255; return p;
  };
  u16*   Wcat  = (u16*)  alloc((size_t)3 * 1280 * 256 * 2);
  u16*   Wet   = (u16*)  alloc((size_t)3 * 256 * 256 * 2);
  u16*   WqBF  = (u16*)  alloc((size_t)3 * 256 * 256 * 2);
  u16*   WeBF  = (u16*)  alloc((size_t)3 * 256 * 256 * 2);
  float* biasc = (float*)alloc((size_t)3 * 1280 * 4);
  u16*   Wnet  = (u16*)  alloc((size_t)256 * 128 * 2);
  u16*   Weet  = (u16*)  alloc((size_t)256 * 32 * 2);
  u16*   xbf   = (u16*)  alloc((size_t)MPN * 128 * 2);
  u16*   eabf  = (u16*)  alloc((size_t)MPE * 32 * 2);
  u16*   hbf   = (u16*)  alloc((size_t)MPN * 256 * 2);
  float* slab  = (float*)alloc((size_t)MPN * 768 * 4);
  u16*   kvbf  = (u16*)  alloc((size_t)MPN * 512 * 2);
  u16*   efp   = (u16*)  alloc((size_t)MPE * 256 * 2);
  int*   cnt   = (int*)  alloc((size_t)NN * 4);
  int*   offs  = (int*)  alloc((size_t)(NN + 1) * 4);
  int*   cursor= (int*)  alloc((size_t)NN * 4);
  int*   bsum  = (int*)  alloc((size_t)64 * 4);
  int*   bpre  = (int*)  alloc((size_t)64 * 4);
  int*   eids  = (int*)  alloc((size_t)EE * 4);
  int*   eidp  = (int*)  alloc((size_t)MPE * 4);
  int*   srcp  = (int*)  alloc((size_t)EE * 4);
  float* accv  = (float*)alloc((size_t)NN * 256 * 4);
  u16*   aggef = (u16*)  alloc((size_t)MPN * 256 * 2);
  if(off > ws_size) return;   // workspace too small -> visible validation failure

  // CSR build (deterministic: rank-by-edge-id, no sort)
  hipMemsetAsync(cnt, 0, (size_t)NN * 4, stream);
  count_k <<<(EE + 255) / 256, 256, 0, stream>>>(dst, cnt);
  scan1_k <<<40, 256, 0, stream>>>(cnt, offs, bsum);
  scan2_k <<<1, 64, 0, stream>>>(bsum, bpre);
  scan3_k <<<40, 256, 0, stream>>>(offs, bpre, cursor);
  scatter_k<<<(EE + 255) / 256, 256, 0, stream>>>(dst, cursor, eids);
  rank_k  <<<(MPE + 255) / 256, 256, 0, stream>>>(dst, src, offs, eids, eidp, srcp);

  // input/weight conversion
  conv_bf16_k<<<(MPN * 128 + 255) / 256, 256, 0, stream>>>(x, xbf, NN * 128, MPN * 128);
  conv_bf16_k<<<(MPE * 32 + 255) / 256, 256, 0, stream>>>(eattr, eabf, EE * 32, MPE * 32);
  prepw_k   <<<3 * 1280, 256, 0, stream>>>(P, Wcat, Wet);
  convW_k   <<<3 * 512, 256, 0, stream>>>(P, WqBF, WeBF);
  prepbias_k<<<15, 256, 0, stream>>>(P, biasc);
  prepenc_k <<<256, 128, 0, stream>>>(Wne, Wee, Wnet, Weet);

  // qWe weight per layer: Wcat sec2 row j, elem k = sum_c We[j,c]*Wq[k,c]
  for(int l = 0; l < 3; ++l)
    gemm_k<64,5><<<dim3(2, 2), 256, 0, stream>>>(
        WeBF + (size_t)l * 256 * 256, WqBF + (size_t)l * 256 * 256, nullptr,
        Wcat + ((size_t)l * 1280 + 512) * 256,
        nullptr, nullptr, nullptr, nullptr, 256, 256, 256);

  // node encoder: h = relu(x @ Wne + bne)  -> bf16
  gemm_k<64,1><<<dim3(MPN / 128, 2), 256, 0, stream>>>(
      xbf, Wnet, bne, hbf, nullptr, nullptr, nullptr, nullptr, NN, 256, 128);
  // edge encoder: ef = relu(edge_attr @ Wee + bee) -> bf16, CSR order via A-gather
  gemm_k<32,1,1><<<dim3(MPE / 128, 2), 256, 0, stream>>>(
      eabf, Weet, bee, efp, nullptr, nullptr, eidp, nullptr, EE, 256, 32);

  for(int l = 0; l < 3; ++l){
    // fused q|skip|qWe (fp32) + k|v (bf16) slab
    gemm_k<64,0><<<dim3(MPN / 128, 10), 256, 0, stream>>>(
        hbf, Wcat + (size_t)l * 1280 * 256, biasc + (size_t)l * 1280, slab,
        nullptr, nullptr, nullptr, kvbf, NN, 768, 256);
    // per-node attention: scores + exp + weighted sums (pre-divided by denom)
    node_pass_k<<<NN / 4, 256, 0, stream>>>(slab, efp, kvbf, srcp, offs, accv, aggef);
    // out = accv + aggef@We + skip  (+relu, bf16 for layers 0,1; fp32 out for layer 2)
    if(l < 2)
      gemm_k<64,3><<<dim3(MPN / 128, 2), 256, 0, stream>>>(
          aggef, Wet + (size_t)l * 256 * 256, nullptr, hbf,
          accv, slab, nullptr, nullptr, NN, 256, 256);
    else
      gemm_k<64,4><<<dim3(MPN / 128, 2), 256, 0, stream>>>(
          aggef, Wet + (size_t)l * 256 * 256, nullptr, d_out,
          accv, slab, nullptr, nullptr, NN, 256, 256);
  }
}

// Round 4
// 382.772 us; speedup vs baseline: 1.8141x; 1.3039x over previous
//
#include <hip/hip_runtime.h>
#include <cstdint>

typedef unsigned short u16;
typedef __attribute__((ext_vector_type(8))) short short8;
typedef __attribute__((ext_vector_type(8))) __bf16 bf16x8;
typedef __attribute__((ext_vector_type(4))) float f32x4;

#define DEV __device__ __forceinline__

DEV u16 f2bf(float f){
  uint32_t u = __float_as_uint(f);
  u += 0x7fffu + ((u >> 16) & 1u);
  return (u16)(u >> 16);
}
DEV float bf2f(u16 h){ return __uint_as_float(((uint32_t)h) << 16); }

DEV f32x4 mfma16(short8 a, short8 b, f32x4 c){
  return __builtin_amdgcn_mfma_f32_16x16x32_bf16(
      __builtin_bit_cast(bf16x8, a), __builtin_bit_cast(bf16x8, b), c, 0, 0, 0);
}

#define NN 10000
#define EE 160000
#define MPN 10112   /* 79*128  */
#define MPE 160128  /* 1251*128 */

// ---------------- utility kernels ----------------
__global__ void conv_bf16_k(const float* __restrict__ in, u16* __restrict__ out,
                            int n_in, int n_tot){
  int i = blockIdx.x * 256 + threadIdx.x;
  if(i < n_tot) out[i] = (i < n_in) ? f2bf(in[i]) : (u16)0;
}

__global__ void count_k(const int* __restrict__ dst, int* __restrict__ cnt){
  int i = blockIdx.x * 256 + threadIdx.x;
  if(i < EE) atomicAdd(&cnt[dst[i]], 1);
}

// hierarchical scan: local 256-scan -> 1-wave scan of 40 block sums -> apply
__global__ void scan1_k(const int* __restrict__ cnt, int* __restrict__ offs,
                        int* __restrict__ bsum){
  __shared__ int buf[256];
  int b = blockIdx.x, tid = threadIdx.x, i = b * 256 + tid;
  int v = (i < NN) ? cnt[i] : 0;
  buf[tid] = v; __syncthreads();
  for(int d = 1; d < 256; d <<= 1){
    int t = (tid >= d) ? buf[tid - d] : 0;
    __syncthreads();
    buf[tid] += t;
    __syncthreads();
  }
  if(i < NN) offs[i] = buf[tid] - v;      // block-local exclusive
  if(tid == 255) bsum[b] = buf[255];
}

__global__ void scan2_k(const int* __restrict__ bsum, int* __restrict__ bpre){
  int t = threadIdx.x;                     // 1 block, 64 threads
  int v = (t < 40) ? bsum[t] : 0;
  int s = v;
  for(int d = 1; d < 64; d <<= 1){
    int o = __shfl_up(s, d);
    if(t >= d) s += o;
  }
  if(t < 40) bpre[t] = s - v;
}

__global__ void scan3_k(int* __restrict__ offs, const int* __restrict__ bpre,
                        int* __restrict__ cursor){
  int b = blockIdx.x, i = b * 256 + threadIdx.x;
  if(i < NN){ int v = offs[i] + bpre[b]; offs[i] = v; cursor[i] = v; }
  if(i == 0) offs[NN] = EE;
}

__global__ void scatter_k(const int* __restrict__ dst, int* __restrict__ cursor,
                          int* __restrict__ eids){
  int i = blockIdx.x * 256 + threadIdx.x;
  if(i < EE){ int p = atomicAdd(&cursor[dst[i]], 1); eids[p] = i; }
}

// deterministic rank: slot(e) = offs[dst] + #{e' in bucket : e' < e}
// writes the INVERSE map eidp[slot] = e  (A-side gather for the edge GEMM)
__global__ void rank_k(const int* __restrict__ dst, const int* __restrict__ src,
                       const int* __restrict__ offs, const int* __restrict__ eids,
                       int* __restrict__ eidp, int* __restrict__ srcp){
  int e = blockIdx.x * 256 + threadIdx.x;
  if(e >= MPE) return;
  if(e >= EE){ eidp[e] = e; return; }      // pad slots -> zero rows of eabf
  int n = dst[e];
  int p0 = offs[n], p1 = offs[n + 1];
  int rk = 0;
  for(int p = p0; p < p1; ++p) rk += (eids[p] < e) ? 1 : 0;
  int slot = p0 + rk;
  eidp[slot] = e;
  srcp[slot] = src[e];
}

// ---------------- weight prep ----------------
struct WPack {
  const float* Wq[3]; const float* Wk[3]; const float* Wv[3];
  const float* Ws[3]; const float* We[3];
  const float* bq[3]; const float* bk[3]; const float* bv[3]; const float* bs[3];
};

// Wcat rows per layer: [0,256) Wq^T | [256,512) Ws^T | [512,768) qWe (GEMM EPI5)
//                      | [768,1024) Wk^T | [1024,1280) Wv^T
__global__ __launch_bounds__(256) void prepw_k(WPack P, u16* __restrict__ Wcat,
                                               u16* __restrict__ Wet){
  int b = blockIdx.x; int l = b / 1280, r = b % 1280; int k = threadIdx.x;
  float v;
  if(r < 256)       v = P.Wq[l][k * 256 + r];
  else if(r < 512)  v = P.Ws[l][k * 256 + (r - 256)];
  else if(r < 768){ Wet[((size_t)l * 256 + (r - 512)) * 256 + k] =
                      f2bf(P.We[l][k * 256 + (r - 512)]); return; }
  else if(r < 1024) v = P.Wk[l][k * 256 + (r - 768)];
  else              v = P.Wv[l][k * 256 + (r - 1024)];
  Wcat[((size_t)l * 1280 + r) * 256 + k] = f2bf(v);
}

// bf16 copies of Wq, We in original [in][out] layout, for the weight GEMM
__global__ void convW_k(WPack P, u16* __restrict__ WqBF, u16* __restrict__ WeBF){
  int b = blockIdx.x; int l = b >> 9, rr = b & 511; int t = threadIdx.x;
  if(rr < 256) WqBF[((size_t)l * 256 + rr) * 256 + t] = f2bf(P.Wq[l][rr * 256 + t]);
  else         WeBF[((size_t)l * 256 + (rr - 256)) * 256 + t] = f2bf(P.We[l][(rr - 256) * 256 + t]);
}

// bias rows per layer (ld 1280): bq | bs | bqWe | bk | bv
__global__ void prepbias_k(WPack P, float* __restrict__ bias_cat){
  int b = blockIdx.x; int l = b / 5, seg = b % 5; int t = threadIdx.x;
  float v;
  if(seg == 0)      v = P.bq[l][t];
  else if(seg == 1) v = P.bs[l][t];
  else if(seg == 2){
    const float* we = P.We[l] + (size_t)t * 256; const float* bq = P.bq[l];
    float s = 0.f;
    for(int c = 0; c < 256; ++c) s += bq[c] * we[c];
    v = s;
  }
  else if(seg == 3) v = P.bk[l][t];
  else              v = P.bv[l][t];
  bias_cat[(size_t)l * 1280 + seg * 256 + t] = v;
}

__global__ void prepenc_k(const float* __restrict__ Wne, const float* __restrict__ Wee,
                          u16* __restrict__ Wnet, u16* __restrict__ Weet){
  int n = blockIdx.x, t = threadIdx.x;   // grid 256, block 128
  Wnet[n * 128 + t] = f2bf(Wne[(size_t)t * 256 + n]);
  if(t < 32) Weet[n * 32 + t] = f2bf(Wee[(size_t)t * 256 + n]);
}

// ---------------- MFMA GEMM:  C[M,N] = A[M,K](bf16) @ Bt[N,K]^T(bf16) ----------------
// AG: gather A rows through rowmap.
// EPI 0: +bias; cols<768 -> fp32 slab; cols>=768 -> bf16 kvout (col-768, ld 512)
// EPI 1: +bias, relu -> bf16
// EPI 3: acc + accv + skip, relu -> bf16   (accv pre-divided by denom)
// EPI 4: acc + accv + skip -> fp32
// EPI 5: plain -> bf16 (weight-prep GEMM)
// All outputs staged in LDS then stored as 16B/lane vectorized chunks.
template<int BK, int EPI, int AG = 0>
__global__ __launch_bounds__(256) void gemm_k(
    const u16* __restrict__ A, const u16* __restrict__ Bt,
    const float* __restrict__ bias, void* __restrict__ Out,
    const float* __restrict__ accv, const float* __restrict__ skipS,
    const int* __restrict__ rowmap, u16* __restrict__ kvout,
    int Mreal, int Nld, int K)
{
  constexpr int CPR = BK / 8;           // 16B chunks per LDS row
  constexpr int SW  = (BK == 64) ? 7 : 3;
  __shared__ short8 smem8[2048];        // 32KB: Al|Bl during K-loop, stage in epilogue
  u16* Al = (u16*)smem8;
  u16* Bl = Al + 128 * BK;
  int tid = threadIdx.x, lane = tid & 63;
  int rowBase = blockIdx.x * 128, colBase = blockIdx.y * 128;
  int wave = tid >> 6, wm = wave >> 1, wn = wave & 1;
  int lr = lane & 15, lk = lane >> 4;
  f32x4 acc[4][4] = {};
  int nkt = K / BK;
  for(int kt = 0; kt < nkt; ++kt){
    __syncthreads();
    for(int ci = tid; ci < 128 * CPR; ci += 256){
      int r = ci / CPR, cb = ci % CPR;
      int ar = AG ? rowmap[rowBase + r] : (rowBase + r);
      int d = (r * CPR + (cb ^ (r & SW))) * 8;     // swizzled dest (u16 units)
      *(short8*)&Al[d] = *(const short8*)&A [(size_t)ar * K + kt * BK + cb * 8];
      *(short8*)&Bl[d] = *(const short8*)&Bt[(size_t)(colBase + r) * K + kt * BK + cb * 8];
    }
    __syncthreads();
    #pragma unroll
    for(int kk = 0; kk < BK / 32; ++kk){
      short8 af[4], bfr[4];
      #pragma unroll
      for(int m = 0; m < 4; ++m){
        int r = wm * 64 + m * 16 + lr;
        int byt = r * (BK * 2) + kk * 64 + lk * 16; byt ^= (r & SW) << 4;
        af[m] = *(const short8*)((const char*)Al + byt);
      }
      #pragma unroll
      for(int n = 0; n < 4; ++n){
        int r = wn * 64 + n * 16 + lr;
        int byt = r * (BK * 2) + kk * 64 + lk * 16; byt ^= (r & SW) << 4;
        bfr[n] = *(const short8*)((const char*)Bl + byt);
      }
      #pragma unroll
      for(int m = 0; m < 4; ++m)
        #pragma unroll
        for(int n = 0; n < 4; ++n)
          acc[m][n] = mfma16(af[m], bfr[n], acc[m][n]);
    }
  }

  // ---------- epilogue: LDS-staged, vectorized 16B stores ----------
  __syncthreads();                       // all ds_reads done before LDS reuse
  if constexpr(EPI == 0 || EPI == 4){
    bool kvside = (EPI == 0) && (colBase >= 768);
    if(kvside){
      u16* us = (u16*)smem8;             // [128][128] bf16
      #pragma unroll
      for(int m = 0; m < 4; ++m)
        #pragma unroll
        for(int n = 0; n < 4; ++n){
          int cc = wn * 64 + n * 16 + lr;
          #pragma unroll
          for(int j = 0; j < 4; ++j){
            int rr = wm * 64 + m * 16 + lk * 4 + j;
            us[rr * 128 + cc] = f2bf(acc[m][n][j] + bias[colBase + cc]);
          }
        }
      __syncthreads();
      for(int ch = tid; ch < 2048; ch += 256){
        int rr = ch >> 4, cc = (ch & 15) << 3;
        int r = rowBase + rr;
        if(r < Mreal)
          *(short8*)&kvout[(size_t)r * 512 + (colBase - 768) + cc] = *(short8*)&us[rr * 128 + cc];
      }
    } else {
      float* fs = (float*)smem8;         // [64][128] fp32, two passes
      #pragma unroll
      for(int h = 0; h < 2; ++h){
        if(wm == h){
          #pragma unroll
          for(int m = 0; m < 4; ++m)
            #pragma unroll
            for(int n = 0; n < 4; ++n){
              int cc = wn * 64 + n * 16 + lr;
              int c = colBase + cc;
              #pragma unroll
              for(int j = 0; j < 4; ++j){
                int r2 = m * 16 + lk * 4 + j;
                float v = acc[m][n][j];
                if constexpr(EPI == 0) v += bias[c];
                else {
                  int r = rowBase + h * 64 + r2;
                  v += accv[(size_t)r * 256 + c] + skipS[(size_t)r * 768 + 256 + c];
                }
                fs[r2 * 128 + cc] = v;
              }
            }
        }
        __syncthreads();
        for(int ch = tid; ch < 2048; ch += 256){
          int rr = ch >> 5, cc = (ch & 31) << 2;
          int r = rowBase + h * 64 + rr;
          if(r < Mreal)
            *(float4*)&((float*)Out)[(size_t)r * Nld + colBase + cc] = *(float4*)&fs[rr * 128 + cc];
        }
        __syncthreads();
      }
    }
  } else {
    // bf16 single-pass: EPI 1 (bias+relu), 3 (accv+skip+relu), 5 (plain)
    u16* us = (u16*)smem8;               // [128][128] bf16
    #pragma unroll
    for(int m = 0; m < 4; ++m)
      #pragma unroll
      for(int n = 0; n < 4; ++n){
        int cc = wn * 64 + n * 16 + lr;
        int c = colBase + cc;
        #pragma unroll
        for(int j = 0; j < 4; ++j){
          int rr = wm * 64 + m * 16 + lk * 4 + j;
          float v = acc[m][n][j];
          if constexpr(EPI == 1){ v += bias[c]; v = fmaxf(v, 0.f); }
          else if constexpr(EPI == 3){
            int r = rowBase + rr;
            v += accv[(size_t)r * 256 + c] + skipS[(size_t)r * 768 + 256 + c];
            v = fmaxf(v, 0.f);
          }
          us[rr * 128 + cc] = f2bf(v);
        }
      }
    __syncthreads();
    for(int ch = tid; ch < 2048; ch += 256){
      int rr = ch >> 4, cc = (ch & 15) << 3;
      int r = rowBase + rr;
      if(r < Mreal)
        *(short8*)&((u16*)Out)[(size_t)r * Nld + colBase + cc] = *(short8*)&us[rr * 128 + cc];
    }
  }
}

// ---------------- fused per-node attention pass ----------------
// slab row (ld 768 fp32): q[0:256) skip[256:512) qWe[512:768)
// kvbf row (ld 512 bf16): k[0:256) v[256:512)
// 4 edges in flight per wave: 16 lanes per edge, 16 dims per lane.
__global__ __launch_bounds__(256) void node_pass_k(
    const float* __restrict__ slab, const u16* __restrict__ efp,
    const u16* __restrict__ kvbf,
    const int* __restrict__ srcp, const int* __restrict__ offs,
    float* __restrict__ accv, u16* __restrict__ aggef)
{
  int wave = threadIdx.x >> 6, lane = threadIdx.x & 63;
  int n = blockIdx.x * 4 + wave;
  if(n >= NN) return;
  int li = lane & 15, eg = lane >> 4;
  const float* qrow = slab + (size_t)n * 768 + li * 16;
  float q[16], e[16];
  #pragma unroll
  for(int t = 0; t < 4; ++t){
    float4 a = *(const float4*)(qrow + t * 4);
    float4 b = *(const float4*)(qrow + 512 + t * 4);
    q[t*4+0] = a.x; q[t*4+1] = a.y; q[t*4+2] = a.z; q[t*4+3] = a.w;
    e[t*4+0] = b.x; e[t*4+1] = b.y; e[t*4+2] = b.z; e[t*4+3] = b.w;
  }
  float av[16], ag[16];
  #pragma unroll
  for(int d = 0; d < 16; ++d){ av[d] = 0.f; ag[d] = 0.f; }
  float den = 0.f;
  int p0 = offs[n], p1 = offs[n + 1];
  for(int p = p0 + eg; p < p1; p += 4){
    int s = srcp[p];
    const u16* kvp = kvbf + (size_t)s * 512 + li * 16;
    const u16* epp = efp + (size_t)p * 256 + li * 16;
    short8 kA = *(const short8*)(kvp);
    short8 kB = *(const short8*)(kvp + 8);
    short8 vA = *(const short8*)(kvp + 256);
    short8 vB = *(const short8*)(kvp + 264);
    short8 fA = *(const short8*)(epp);
    short8 fB = *(const short8*)(epp + 8);
    float part = 0.f;
    #pragma unroll
    for(int d = 0; d < 8; ++d){
      part += q[d]   * bf2f((u16)kA[d]) + e[d]   * bf2f((u16)fA[d]);
      part += q[8+d] * bf2f((u16)kB[d]) + e[8+d] * bf2f((u16)fB[d]);
    }
    part += __shfl_xor(part, 1);
    part += __shfl_xor(part, 2);
    part += __shfl_xor(part, 4);
    part += __shfl_xor(part, 8);
    float wgt = __expf(part * 0.0625f);            // /sqrt(256)
    den += wgt;
    #pragma unroll
    for(int d = 0; d < 8; ++d){
      av[d]   += wgt * bf2f((u16)vA[d]);
      av[8+d] += wgt * bf2f((u16)vB[d]);
      ag[d]   += wgt * bf2f((u16)fA[d]);
      ag[8+d] += wgt * bf2f((u16)fB[d]);
    }
  }
  // combine the 4 edge-groups
  #pragma unroll
  for(int d = 0; d < 16; ++d){
    av[d] += __shfl_xor(av[d], 16); av[d] += __shfl_xor(av[d], 32);
    ag[d] += __shfl_xor(ag[d], 16); ag[d] += __shfl_xor(ag[d], 32);
  }
  den += __shfl_xor(den, 16); den += __shfl_xor(den, 32);
  float rden = 1.f / fmaxf(den, 1e-16f);          // pre-divide (linear in We)
  if(eg == 0){
    float* ao = accv + (size_t)n * 256 + li * 16;
    #pragma unroll
    for(int t = 0; t < 4; ++t){
      float4 o;
      o.x = av[t*4+0] * rden; o.y = av[t*4+1] * rden;
      o.z = av[t*4+2] * rden; o.w = av[t*4+3] * rden;
      *(float4*)(ao + t * 4) = o;
    }
  } else if(eg == 1){
    u16* go = aggef + (size_t)n * 256 + li * 16;
    #pragma unroll
    for(int t = 0; t < 2; ++t){
      short8 o;
      #pragma unroll
      for(int d = 0; d < 8; ++d) o[d] = (short)f2bf(ag[t*8+d] * rden);
      *(short8*)(go + t * 8) = o;
    }
  }
}

// ---------------- launch ----------------
extern "C" void kernel_launch(void* const* d_in, const int* in_sizes, int n_in,
                              void* d_out, int out_size, void* d_ws, size_t ws_size,
                              hipStream_t stream){
  const float* x     = (const float*)d_in[0];
  const float* eattr = (const float*)d_in[1];
  const int*   src   = (const int*)d_in[2];
  const int*   dst   = (const int*)d_in[3];
  const float* Wee   = (const float*)d_in[4];
  const float* bee   = (const float*)d_in[5];
  const float* Wne   = (const float*)d_in[6];
  const float* bne   = (const float*)d_in[7];
  WPack P;
  for(int l = 0; l < 3; ++l){
    const int b = 8 + l * 9;
    P.Wq[l] = (const float*)d_in[b + 0]; P.bq[l] = (const float*)d_in[b + 1];
    P.Wk[l] = (const float*)d_in[b + 2]; P.bk[l] = (const float*)d_in[b + 3];
    P.Wv[l] = (const float*)d_in[b + 4]; P.bv[l] = (const float*)d_in[b + 5];
    P.We[l] = (const float*)d_in[b + 6];
    P.Ws[l] = (const float*)d_in[b + 7]; P.bs[l] = (const float*)d_in[b + 8];
  }

  char* w = (char*)d_ws; size_t off = 0;
  auto alloc = [&](size_t bytes)->char*{
    char* p = w + off; off = (off + bytes + 255) & ~(size_t)255; return p;
  };
  u16*   Wcat  = (u16*)  alloc((size_t)3 * 1280 * 256 * 2);
  u16*   Wet   = (u16*)  alloc((size_t)3 * 256 * 256 * 2);
  u16*   WqBF  = (u16*)  alloc((size_t)3 * 256 * 256 * 2);
  u16*   WeBF  = (u16*)  alloc((size_t)3 * 256 * 256 * 2);
  float* biasc = (float*)alloc((size_t)3 * 1280 * 4);
  u16*   Wnet  = (u16*)  alloc((size_t)256 * 128 * 2);
  u16*   Weet  = (u16*)  alloc((size_t)256 * 32 * 2);
  u16*   xbf   = (u16*)  alloc((size_t)MPN * 128 * 2);
  u16*   eabf  = (u16*)  alloc((size_t)MPE * 32 * 2);
  u16*   hbf   = (u16*)  alloc((size_t)MPN * 256 * 2);
  float* slab  = (float*)alloc((size_t)MPN * 768 * 4);
  u16*   kvbf  = (u16*)  alloc((size_t)MPN * 512 * 2);
  u16*   efp   = (u16*)  alloc((size_t)MPE * 256 * 2);
  int*   cnt   = (int*)  alloc((size_t)NN * 4);
  int*   offs  = (int*)  alloc((size_t)(NN + 1) * 4);
  int*   cursor= (int*)  alloc((size_t)NN * 4);
  int*   bsum  = (int*)  alloc((size_t)64 * 4);
  int*   bpre  = (int*)  alloc((size_t)64 * 4);
  int*   eids  = (int*)  alloc((size_t)EE * 4);
  int*   eidp  = (int*)  alloc((size_t)MPE * 4);
  int*   srcp  = (int*)  alloc((size_t)EE * 4);
  float* accv  = (float*)alloc((size_t)MPN * 256 * 4);
  u16*   aggef = (u16*)  alloc((size_t)MPN * 256 * 2);
  if(off > ws_size) return;   // workspace too small -> visible validation failure

  // CSR build (deterministic: rank-by-edge-id, no sort)
  hipMemsetAsync(cnt, 0, (size_t)NN * 4, stream);
  count_k <<<(EE + 255) / 256, 256, 0, stream>>>(dst, cnt);
  scan1_k <<<40, 256, 0, stream>>>(cnt, offs, bsum);
  scan2_k <<<1, 64, 0, stream>>>(bsum, bpre);
  scan3_k <<<40, 256, 0, stream>>>(offs, bpre, cursor);
  scatter_k<<<(EE + 255) / 256, 256, 0, stream>>>(dst, cursor, eids);
  rank_k  <<<(MPE + 255) / 256, 256, 0, stream>>>(dst, src, offs, eids, eidp, srcp);

  // input/weight conversion
  conv_bf16_k<<<(MPN * 128 + 255) / 256, 256, 0, stream>>>(x, xbf, NN * 128, MPN * 128);
  conv_bf16_k<<<(MPE * 32 + 255) / 256, 256, 0, stream>>>(eattr, eabf, EE * 32, MPE * 32);
  prepw_k   <<<3 * 1280, 256, 0, stream>>>(P, Wcat, Wet);
  convW_k   <<<3 * 512, 256, 0, stream>>>(P, WqBF, WeBF);
  prepbias_k<<<15, 256, 0, stream>>>(P, biasc);
  prepenc_k <<<256, 128, 0, stream>>>(Wne, Wee, Wnet, Weet);

  // qWe weight per layer: Wcat sec2 row j, elem k = sum_c We[j,c]*Wq[k,c]
  for(int l = 0; l < 3; ++l)
    gemm_k<64,5><<<dim3(2, 2), 256, 0, stream>>>(
        WeBF + (size_t)l * 256 * 256, WqBF + (size_t)l * 256 * 256, nullptr,
        Wcat + ((size_t)l * 1280 + 512) * 256,
        nullptr, nullptr, nullptr, nullptr, 256, 256, 256);

  // node encoder: h = relu(x @ Wne + bne)  -> bf16
  gemm_k<64,1><<<dim3(MPN / 128, 2), 256, 0, stream>>>(
      xbf, Wnet, bne, hbf, nullptr, nullptr, nullptr, nullptr, NN, 256, 128);
  // edge encoder: ef = relu(edge_attr @ Wee + bee) -> bf16, CSR order via A-gather
  gemm_k<32,1,1><<<dim3(MPE / 128, 2), 256, 0, stream>>>(
      eabf, Weet, bee, efp, nullptr, nullptr, eidp, nullptr, EE, 256, 32);

  for(int l = 0; l < 3; ++l){
    // fused q|skip|qWe (fp32) + k|v (bf16) slab
    gemm_k<64,0><<<dim3(MPN / 128, 10), 256, 0, stream>>>(
        hbf, Wcat + (size_t)l * 1280 * 256, biasc + (size_t)l * 1280, slab,
        nullptr, nullptr, nullptr, kvbf, NN, 768, 256);
    // per-node attention: scores + exp + weighted sums (pre-divided by denom)
    node_pass_k<<<NN / 4, 256, 0, stream>>>(slab, efp, kvbf, srcp, offs, accv, aggef);
    // out = accv + aggef@We + skip  (+relu, bf16 for layers 0,1; fp32 out for layer 2)
    if(l < 2)
      gemm_k<64,3><<<dim3(MPN / 128, 2), 256, 0, stream>>>(
          aggef, Wet + (size_t)l * 256 * 256, nullptr, hbf,
          accv, slab, nullptr, nullptr, NN, 256, 256);
    else
      gemm_k<64,4><<<dim3(MPN / 128, 2), 256, 0, stream>>>(
          aggef, Wet + (size_t)l * 256 * 256, nullptr, d_out,
          accv, slab, nullptr, nullptr, NN, 256, 256);
  }
}

// Round 5
// 353.144 us; speedup vs baseline: 1.9663x; 1.0839x over previous
//
#include <hip/hip_runtime.h>
#include <cstdint>

typedef unsigned short u16;
typedef __attribute__((ext_vector_type(8))) short short8;
typedef __attribute__((ext_vector_type(8))) __bf16 bf16x8;
typedef __attribute__((ext_vector_type(4))) float f32x4;

#define DEV __device__ __forceinline__

DEV u16 f2bf(float f){
  uint32_t u = __float_as_uint(f);
  u += 0x7fffu + ((u >> 16) & 1u);
  return (u16)(u >> 16);
}
DEV float bf2f(u16 h){ return __uint_as_float(((uint32_t)h) << 16); }

DEV f32x4 mfma16(short8 a, short8 b, f32x4 c){
  return __builtin_amdgcn_mfma_f32_16x16x32_bf16(
      __builtin_bit_cast(bf16x8, a), __builtin_bit_cast(bf16x8, b), c, 0, 0, 0);
}

#define NN 10000
#define EE 160000
#define MPN 10112   /* 79*128  */
#define MPE 160128  /* 1251*128 */

// ---------------- CSR build ----------------
__global__ void count_k(const int* __restrict__ dst, int* __restrict__ cnt){
  int i = blockIdx.x * 256 + threadIdx.x;
  if(i < EE) atomicAdd(&cnt[dst[i]], 1);
}

__global__ void scan1_k(const int* __restrict__ cnt, int* __restrict__ offs,
                        int* __restrict__ bsum){
  __shared__ int buf[256];
  int b = blockIdx.x, tid = threadIdx.x, i = b * 256 + tid;
  int v = (i < NN) ? cnt[i] : 0;
  buf[tid] = v; __syncthreads();
  for(int d = 1; d < 256; d <<= 1){
    int t = (tid >= d) ? buf[tid - d] : 0;
    __syncthreads();
    buf[tid] += t;
    __syncthreads();
  }
  if(i < NN) offs[i] = buf[tid] - v;      // block-local exclusive
  if(tid == 255) bsum[b] = buf[255];
}

// scan of 40 block sums fused into the apply kernel (40 serial adds on lane 0)
__global__ void scan23_k(int* __restrict__ offs, const int* __restrict__ bsum,
                         int* __restrict__ cursor){
  __shared__ int bpre_s;
  int b = blockIdx.x, tid = threadIdx.x;
  if(tid == 0){
    int s = 0;
    for(int i = 0; i < b; ++i) s += bsum[i];
    bpre_s = s;
  }
  __syncthreads();
  int i = b * 256 + tid;
  if(i < NN){ int v = offs[i] + bpre_s; offs[i] = v; cursor[i] = v; }
  if(i == 0) offs[NN] = EE;
}

__global__ void scatter_k(const int* __restrict__ dst, int* __restrict__ cursor,
                          int* __restrict__ eids){
  int i = blockIdx.x * 256 + threadIdx.x;
  if(i < EE){ int p = atomicAdd(&cursor[dst[i]], 1); eids[p] = i; }
}

// deterministic rank: slot(e) = offs[dst] + #{e' in bucket : e' < e}
__global__ void rank_k(const int* __restrict__ dst, const int* __restrict__ src,
                       const int* __restrict__ offs, const int* __restrict__ eids,
                       int* __restrict__ eidp, int* __restrict__ srcp){
  int e = blockIdx.x * 256 + threadIdx.x;
  if(e >= MPE) return;
  if(e >= EE){ eidp[e] = e; return; }      // pad slots -> zero rows of eabf
  int n = dst[e];
  int p0 = offs[n], p1 = offs[n + 1];
  int rk = 0;
  for(int p = p0; p < p1; ++p) rk += (eids[p] < e) ? 1 : 0;
  int slot = p0 + rk;
  eidp[slot] = e;
  srcp[slot] = src[e];
}

// ---------------- weight / input prep (single fused kernel) ----------------
struct WPack {
  const float* Wq[3]; const float* Wk[3]; const float* Wv[3];
  const float* Ws[3]; const float* We[3];
  const float* bq[3]; const float* bk[3]; const float* bv[3]; const float* bs[3];
};

#define PG0 5056                 /* xbf   : MPN*128/256 */
#define PG1 (PG0 + 20016)        /* eabf  : MPE*32/256  */
#define PG2 (PG1 + 3840)         /* Wcat/Wet : 3*1280   */
#define PG3 (PG2 + 1536)         /* WqBF/WeBF: 3*512    */
#define PG4 (PG3 + 15)           /* biasc */
#define PG5 (PG4 + 256)          /* encoders */

// Wcat rows per layer: [0,256) Wq^T | [256,512) Ws^T | [512,768) qWe (GEMM EPI5)
//                      | [768,1024) Wk^T | [1024,1280) Wv^T
__global__ __launch_bounds__(256) void prep_all_k(
    const float* __restrict__ x, const float* __restrict__ eattr, WPack P,
    const float* __restrict__ Wne, const float* __restrict__ Wee,
    u16* __restrict__ xbf, u16* __restrict__ eabf,
    u16* __restrict__ Wcat, u16* __restrict__ Wet,
    u16* __restrict__ WqBF, u16* __restrict__ WeBF,
    float* __restrict__ biasc, u16* __restrict__ Wnet, u16* __restrict__ Weet)
{
  int b = blockIdx.x, tid = threadIdx.x;
  if(b < PG0){
    int i = b * 256 + tid;
    xbf[i] = (i < NN * 128) ? f2bf(x[i]) : (u16)0;
  } else if(b < PG1){
    int i = (b - PG0) * 256 + tid;
    eabf[i] = (i < EE * 32) ? f2bf(eattr[i]) : (u16)0;
  } else if(b < PG2){
    int b2 = b - PG1; int l = b2 / 1280, r = b2 % 1280; int k = tid;
    float v;
    if(r < 256)       v = P.Wq[l][k * 256 + r];
    else if(r < 512)  v = P.Ws[l][k * 256 + (r - 256)];
    else if(r < 768){ Wet[((size_t)l * 256 + (r - 512)) * 256 + k] =
                        f2bf(P.We[l][k * 256 + (r - 512)]); return; }
    else if(r < 1024) v = P.Wk[l][k * 256 + (r - 768)];
    else              v = P.Wv[l][k * 256 + (r - 1024)];
    Wcat[((size_t)l * 1280 + r) * 256 + k] = f2bf(v);
  } else if(b < PG3){
    int b3 = b - PG2; int l = b3 >> 9, rr = b3 & 511; int t = tid;
    if(rr < 256) WqBF[((size_t)l * 256 + rr) * 256 + t] = f2bf(P.Wq[l][rr * 256 + t]);
    else         WeBF[((size_t)l * 256 + (rr - 256)) * 256 + t] = f2bf(P.We[l][(rr - 256) * 256 + t]);
  } else if(b < PG4){
    int b4 = b - PG3; int l = b4 / 5, seg = b4 % 5; int t = tid;
    float v;
    if(seg == 0)      v = P.bq[l][t];
    else if(seg == 1) v = P.bs[l][t];
    else if(seg == 2){
      const float* we = P.We[l] + (size_t)t * 256; const float* bq = P.bq[l];
      float s = 0.f;
      for(int c = 0; c < 256; ++c) s += bq[c] * we[c];
      v = s;
    }
    else if(seg == 3) v = P.bk[l][t];
    else              v = P.bv[l][t];
    biasc[(size_t)l * 1280 + seg * 256 + t] = v;
  } else {
    int n = b - PG4;
    if(tid < 128) Wnet[n * 128 + tid] = f2bf(Wne[(size_t)tid * 256 + n]);
    if(tid < 32)  Weet[n * 32 + tid]  = f2bf(Wee[(size_t)tid * 256 + n]);
  }
}

// ---------------- MFMA GEMM:  C[M,N] = A[M,K](bf16) @ Bt[N,K]^T(bf16) ----------------
// AG: gather A rows through rowmap.
// EPI 0: +bias; cols<768 -> fp32 slab; cols>=768 -> bf16 kvout (col-768, ld 512)
// EPI 1: +bias, relu -> bf16
// EPI 3: acc + accv + skip, relu -> bf16   (accv pre-divided by denom)
// EPI 4: acc + accv + skip -> fp32
// EPI 5: plain -> bf16 (weight-prep GEMM; batched over blockIdx.z)
// All outputs staged in LDS then stored as 16B/lane vectorized chunks.
template<int BK, int EPI, int AG = 0>
__global__ __launch_bounds__(256) void gemm_k(
    const u16* __restrict__ A, const u16* __restrict__ Bt,
    const float* __restrict__ bias, void* __restrict__ Out,
    const float* __restrict__ accv, const float* __restrict__ skipS,
    const int* __restrict__ rowmap, u16* __restrict__ kvout,
    int Mreal, int Nld, int K, size_t sA, size_t sB, size_t sOb)
{
  constexpr int CPR = BK / 8;           // 16B chunks per LDS row
  constexpr int SW  = (BK == 64) ? 7 : 3;
  __shared__ short8 smem8[2048];        // 32KB: Al|Bl during K-loop, stage in epilogue
  u16* Al = (u16*)smem8;
  u16* Bl = Al + 128 * BK;
  A  += (size_t)blockIdx.z * sA;
  Bt += (size_t)blockIdx.z * sB;
  Out = (void*)((char*)Out + (size_t)blockIdx.z * sOb);
  int tid = threadIdx.x, lane = tid & 63;
  int rowBase = blockIdx.x * 128, colBase = blockIdx.y * 128;
  int wave = tid >> 6, wm = wave >> 1, wn = wave & 1;
  int lr = lane & 15, lk = lane >> 4;
  f32x4 acc[4][4] = {};
  int nkt = K / BK;
  for(int kt = 0; kt < nkt; ++kt){
    __syncthreads();
    for(int ci = tid; ci < 128 * CPR; ci += 256){
      int r = ci / CPR, cb = ci % CPR;
      int ar = AG ? rowmap[rowBase + r] : (rowBase + r);
      int d = (r * CPR + (cb ^ (r & SW))) * 8;     // swizzled dest (u16 units)
      *(short8*)&Al[d] = *(const short8*)&A [(size_t)ar * K + kt * BK + cb * 8];
      *(short8*)&Bl[d] = *(const short8*)&Bt[(size_t)(colBase + r) * K + kt * BK + cb * 8];
    }
    __syncthreads();
    #pragma unroll
    for(int kk = 0; kk < BK / 32; ++kk){
      short8 af[4], bfr[4];
      #pragma unroll
      for(int m = 0; m < 4; ++m){
        int r = wm * 64 + m * 16 + lr;
        int byt = r * (BK * 2) + kk * 64 + lk * 16; byt ^= (r & SW) << 4;
        af[m] = *(const short8*)((const char*)Al + byt);
      }
      #pragma unroll
      for(int n = 0; n < 4; ++n){
        int r = wn * 64 + n * 16 + lr;
        int byt = r * (BK * 2) + kk * 64 + lk * 16; byt ^= (r & SW) << 4;
        bfr[n] = *(const short8*)((const char*)Bl + byt);
      }
      #pragma unroll
      for(int m = 0; m < 4; ++m)
        #pragma unroll
        for(int n = 0; n < 4; ++n)
          acc[m][n] = mfma16(af[m], bfr[n], acc[m][n]);
    }
  }

  // ---------- epilogue: LDS-staged, vectorized 16B stores ----------
  __syncthreads();                       // all ds_reads done before LDS reuse
  if constexpr(EPI == 0 || EPI == 4){
    bool kvside = (EPI == 0) && (colBase >= 768);
    if(kvside){
      u16* us = (u16*)smem8;             // [128][128] bf16
      #pragma unroll
      for(int m = 0; m < 4; ++m)
        #pragma unroll
        for(int n = 0; n < 4; ++n){
          int cc = wn * 64 + n * 16 + lr;
          #pragma unroll
          for(int j = 0; j < 4; ++j){
            int rr = wm * 64 + m * 16 + lk * 4 + j;
            us[rr * 128 + cc] = f2bf(acc[m][n][j] + bias[colBase + cc]);
          }
        }
      __syncthreads();
      for(int ch = tid; ch < 2048; ch += 256){
        int rr = ch >> 4, cc = (ch & 15) << 3;
        int r = rowBase + rr;
        if(r < Mreal)
          *(short8*)&kvout[(size_t)r * 512 + (colBase - 768) + cc] = *(short8*)&us[rr * 128 + cc];
      }
    } else {
      float* fs = (float*)smem8;         // [64][128] fp32, two passes
      #pragma unroll
      for(int h = 0; h < 2; ++h){
        if(wm == h){
          #pragma unroll
          for(int m = 0; m < 4; ++m)
            #pragma unroll
            for(int n = 0; n < 4; ++n){
              int cc = wn * 64 + n * 16 + lr;
              int c = colBase + cc;
              #pragma unroll
              for(int j = 0; j < 4; ++j){
                int r2 = m * 16 + lk * 4 + j;
                float v = acc[m][n][j];
                if constexpr(EPI == 0) v += bias[c];
                else {
                  int r = rowBase + h * 64 + r2;
                  v += accv[(size_t)r * 256 + c] + skipS[(size_t)r * 768 + 256 + c];
                }
                fs[r2 * 128 + cc] = v;
              }
            }
        }
        __syncthreads();
        for(int ch = tid; ch < 2048; ch += 256){
          int rr = ch >> 5, cc = (ch & 31) << 2;
          int r = rowBase + h * 64 + rr;
          if(r < Mreal)
            *(float4*)&((float*)Out)[(size_t)r * Nld + colBase + cc] = *(float4*)&fs[rr * 128 + cc];
        }
        __syncthreads();
      }
    }
  } else {
    // bf16 single-pass: EPI 1 (bias+relu), 3 (accv+skip+relu), 5 (plain)
    u16* us = (u16*)smem8;               // [128][128] bf16
    #pragma unroll
    for(int m = 0; m < 4; ++m)
      #pragma unroll
      for(int n = 0; n < 4; ++n){
        int cc = wn * 64 + n * 16 + lr;
        int c = colBase + cc;
        #pragma unroll
        for(int j = 0; j < 4; ++j){
          int rr = wm * 64 + m * 16 + lk * 4 + j;
          float v = acc[m][n][j];
          if constexpr(EPI == 1){ v += bias[c]; v = fmaxf(v, 0.f); }
          else if constexpr(EPI == 3){
            int r = rowBase + rr;
            v += accv[(size_t)r * 256 + c] + skipS[(size_t)r * 768 + 256 + c];
            v = fmaxf(v, 0.f);
          }
          us[rr * 128 + cc] = f2bf(v);
        }
      }
    __syncthreads();
    for(int ch = tid; ch < 2048; ch += 256){
      int rr = ch >> 4, cc = (ch & 15) << 3;
      int r = rowBase + rr;
      if(r < Mreal)
        *(short8*)&((u16*)Out)[(size_t)r * Nld + colBase + cc] = *(short8*)&us[rr * 128 + cc];
    }
  }
}

// ---------------- fused per-node attention pass ----------------
// slab row (ld 768 fp32): q[0:256) skip[256:512) qWe[512:768)
// kvbf row (ld 512 bf16): k[0:256) v[256:512)
// 16 lanes per edge; 2-edge unroll -> 8 independent edge streams per wave.
__global__ __launch_bounds__(256) void node_pass_k(
    const float* __restrict__ slab, const u16* __restrict__ efp,
    const u16* __restrict__ kvbf,
    const int* __restrict__ srcp, const int* __restrict__ offs,
    float* __restrict__ accv, u16* __restrict__ aggef)
{
  int wave = threadIdx.x >> 6, lane = threadIdx.x & 63;
  int n = blockIdx.x * 4 + wave;
  if(n >= NN) return;
  int li = lane & 15, eg = lane >> 4;
  const float* qrow = slab + (size_t)n * 768 + li * 16;
  float q[16], e[16];
  #pragma unroll
  for(int t = 0; t < 4; ++t){
    float4 a = *(const float4*)(qrow + t * 4);
    float4 b = *(const float4*)(qrow + 512 + t * 4);
    q[t*4+0] = a.x; q[t*4+1] = a.y; q[t*4+2] = a.z; q[t*4+3] = a.w;
    e[t*4+0] = b.x; e[t*4+1] = b.y; e[t*4+2] = b.z; e[t*4+3] = b.w;
  }
  float av[16], ag[16];
  #pragma unroll
  for(int d = 0; d < 16; ++d){ av[d] = 0.f; ag[d] = 0.f; }
  float den = 0.f;
  int p0 = offs[n], pe = offs[n + 1];
  int p = p0 + eg;
  for(; p + 4 < pe; p += 8){
    int s1 = srcp[p], s2 = srcp[p + 4];
    const u16* kv1 = kvbf + ((size_t)s1 << 9) + li * 16;
    const u16* kv2 = kvbf + ((size_t)s2 << 9) + li * 16;
    const u16* ef1 = efp + ((size_t)p << 8) + li * 16;
    const u16* ef2 = efp + ((size_t)(p + 4) << 8) + li * 16;
    short8 kA1 = *(const short8*)(kv1),       kB1 = *(const short8*)(kv1 + 8);
    short8 vA1 = *(const short8*)(kv1 + 256), vB1 = *(const short8*)(kv1 + 264);
    short8 fA1 = *(const short8*)(ef1),       fB1 = *(const short8*)(ef1 + 8);
    short8 kA2 = *(const short8*)(kv2),       kB2 = *(const short8*)(kv2 + 8);
    short8 vA2 = *(const short8*)(kv2 + 256), vB2 = *(const short8*)(kv2 + 264);
    short8 fA2 = *(const short8*)(ef2),       fB2 = *(const short8*)(ef2 + 8);
    float sc1 = 0.f, sc2 = 0.f;
    #pragma unroll
    for(int d = 0; d < 8; ++d){
      sc1 += q[d]   * bf2f((u16)kA1[d]) + e[d]   * bf2f((u16)fA1[d]);
      sc1 += q[8+d] * bf2f((u16)kB1[d]) + e[8+d] * bf2f((u16)fB1[d]);
      sc2 += q[d]   * bf2f((u16)kA2[d]) + e[d]   * bf2f((u16)fA2[d]);
      sc2 += q[8+d] * bf2f((u16)kB2[d]) + e[8+d] * bf2f((u16)fB2[d]);
    }
    sc1 += __shfl_xor(sc1, 1); sc2 += __shfl_xor(sc2, 1);
    sc1 += __shfl_xor(sc1, 2); sc2 += __shfl_xor(sc2, 2);
    sc1 += __shfl_xor(sc1, 4); sc2 += __shfl_xor(sc2, 4);
    sc1 += __shfl_xor(sc1, 8); sc2 += __shfl_xor(sc2, 8);
    float w1 = __expf(sc1 * 0.0625f);
    float w2 = __expf(sc2 * 0.0625f);
    den += w1 + w2;
    #pragma unroll
    for(int d = 0; d < 8; ++d){
      av[d]   += w1 * bf2f((u16)vA1[d]) + w2 * bf2f((u16)vA2[d]);
      av[8+d] += w1 * bf2f((u16)vB1[d]) + w2 * bf2f((u16)vB2[d]);
      ag[d]   += w1 * bf2f((u16)fA1[d]) + w2 * bf2f((u16)fA2[d]);
      ag[8+d] += w1 * bf2f((u16)fB1[d]) + w2 * bf2f((u16)fB2[d]);
    }
  }
  if(p < pe){
    int s = srcp[p];
    const u16* kvp = kvbf + ((size_t)s << 9) + li * 16;
    const u16* epp = efp + ((size_t)p << 8) + li * 16;
    short8 kA = *(const short8*)(kvp);
    short8 kB = *(const short8*)(kvp + 8);
    short8 vA = *(const short8*)(kvp + 256);
    short8 vB = *(const short8*)(kvp + 264);
    short8 fA = *(const short8*)(epp);
    short8 fB = *(const short8*)(epp + 8);
    float part = 0.f;
    #pragma unroll
    for(int d = 0; d < 8; ++d){
      part += q[d]   * bf2f((u16)kA[d]) + e[d]   * bf2f((u16)fA[d]);
      part += q[8+d] * bf2f((u16)kB[d]) + e[8+d] * bf2f((u16)fB[d]);
    }
    part += __shfl_xor(part, 1);
    part += __shfl_xor(part, 2);
    part += __shfl_xor(part, 4);
    part += __shfl_xor(part, 8);
    float wgt = __expf(part * 0.0625f);
    den += wgt;
    #pragma unroll
    for(int d = 0; d < 8; ++d){
      av[d]   += wgt * bf2f((u16)vA[d]);
      av[8+d] += wgt * bf2f((u16)vB[d]);
      ag[d]   += wgt * bf2f((u16)fA[d]);
      ag[8+d] += wgt * bf2f((u16)fB[d]);
    }
  }
  // combine the 4 edge-groups
  #pragma unroll
  for(int d = 0; d < 16; ++d){
    av[d] += __shfl_xor(av[d], 16); av[d] += __shfl_xor(av[d], 32);
    ag[d] += __shfl_xor(ag[d], 16); ag[d] += __shfl_xor(ag[d], 32);
  }
  den += __shfl_xor(den, 16); den += __shfl_xor(den, 32);
  float rden = 1.f / fmaxf(den, 1e-16f);          // pre-divide (linear in We)
  if(eg == 0){
    float* ao = accv + (size_t)n * 256 + li * 16;
    #pragma unroll
    for(int t = 0; t < 4; ++t){
      float4 o;
      o.x = av[t*4+0] * rden; o.y = av[t*4+1] * rden;
      o.z = av[t*4+2] * rden; o.w = av[t*4+3] * rden;
      *(float4*)(ao + t * 4) = o;
    }
  } else if(eg == 1){
    u16* go = aggef + (size_t)n * 256 + li * 16;
    #pragma unroll
    for(int t = 0; t < 2; ++t){
      short8 o;
      #pragma unroll
      for(int d = 0; d < 8; ++d) o[d] = (short)f2bf(ag[t*8+d] * rden);
      *(short8*)(go + t * 8) = o;
    }
  }
}

// ---------------- launch ----------------
extern "C" void kernel_launch(void* const* d_in, const int* in_sizes, int n_in,
                              void* d_out, int out_size, void* d_ws, size_t ws_size,
                              hipStream_t stream){
  const float* x     = (const float*)d_in[0];
  const float* eattr = (const float*)d_in[1];
  const int*   src   = (const int*)d_in[2];
  const int*   dst   = (const int*)d_in[3];
  const float* Wee   = (const float*)d_in[4];
  const float* bee   = (const float*)d_in[5];
  const float* Wne   = (const float*)d_in[6];
  const float* bne   = (const float*)d_in[7];
  WPack P;
  for(int l = 0; l < 3; ++l){
    const int b = 8 + l * 9;
    P.Wq[l] = (const float*)d_in[b + 0]; P.bq[l] = (const float*)d_in[b + 1];
    P.Wk[l] = (const float*)d_in[b + 2]; P.bk[l] = (const float*)d_in[b + 3];
    P.Wv[l] = (const float*)d_in[b + 4]; P.bv[l] = (const float*)d_in[b + 5];
    P.We[l] = (const float*)d_in[b + 6];
    P.Ws[l] = (const float*)d_in[b + 7]; P.bs[l] = (const float*)d_in[b + 8];
  }

  char* w = (char*)d_ws; size_t off = 0;
  auto alloc = [&](size_t bytes)->char*{
    char* p = w + off; off = (off + bytes + 255) & ~(size_t)255; return p;
  };
  u16*   Wcat  = (u16*)  alloc((size_t)3 * 1280 * 256 * 2);
  u16*   Wet   = (u16*)  alloc((size_t)3 * 256 * 256 * 2);
  u16*   WqBF  = (u16*)  alloc((size_t)3 * 256 * 256 * 2);
  u16*   WeBF  = (u16*)  alloc((size_t)3 * 256 * 256 * 2);
  float* biasc = (float*)alloc((size_t)3 * 1280 * 4);
  u16*   Wnet  = (u16*)  alloc((size_t)256 * 128 * 2);
  u16*   Weet  = (u16*)  alloc((size_t)256 * 32 * 2);
  u16*   xbf   = (u16*)  alloc((size_t)MPN * 128 * 2);
  u16*   eabf  = (u16*)  alloc((size_t)MPE * 32 * 2);
  u16*   hbf   = (u16*)  alloc((size_t)MPN * 256 * 2);
  float* slab  = (float*)alloc((size_t)MPN * 768 * 4);
  u16*   kvbf  = (u16*)  alloc((size_t)MPN * 512 * 2);
  u16*   efp   = (u16*)  alloc((size_t)MPE * 256 * 2);
  int*   cnt   = (int*)  alloc((size_t)NN * 4);
  int*   offs  = (int*)  alloc((size_t)(NN + 1) * 4);
  int*   cursor= (int*)  alloc((size_t)NN * 4);
  int*   bsum  = (int*)  alloc((size_t)64 * 4);
  int*   eids  = (int*)  alloc((size_t)EE * 4);
  int*   eidp  = (int*)  alloc((size_t)MPE * 4);
  int*   srcp  = (int*)  alloc((size_t)EE * 4);
  float* accv  = (float*)alloc((size_t)MPN * 256 * 4);
  u16*   aggef = (u16*)  alloc((size_t)MPN * 256 * 2);
  if(off > ws_size) return;   // workspace too small -> visible validation failure

  // CSR build (deterministic: rank-by-edge-id, no sort)
  hipMemsetAsync(cnt, 0, (size_t)NN * 4, stream);
  count_k <<<(EE + 255) / 256, 256, 0, stream>>>(dst, cnt);
  scan1_k <<<40, 256, 0, stream>>>(cnt, offs, bsum);
  scan23_k<<<40, 256, 0, stream>>>(offs, bsum, cursor);
  scatter_k<<<(EE + 255) / 256, 256, 0, stream>>>(dst, cursor, eids);
  rank_k  <<<(MPE + 255) / 256, 256, 0, stream>>>(dst, src, offs, eids, eidp, srcp);

  // all input/weight conversion in one launch
  prep_all_k<<<PG5, 256, 0, stream>>>(x, eattr, P, Wne, Wee,
      xbf, eabf, Wcat, Wet, WqBF, WeBF, biasc, Wnet, Weet);

  // qWe weight for all 3 layers in one launch (blockIdx.z = layer)
  gemm_k<64,5><<<dim3(2, 2, 3), 256, 0, stream>>>(
      WeBF, WqBF, nullptr, Wcat + (size_t)512 * 256,
      nullptr, nullptr, nullptr, nullptr, 256, 256, 256,
      (size_t)256 * 256, (size_t)256 * 256, (size_t)1280 * 256 * 2);

  // node encoder: h = relu(x @ Wne + bne)  -> bf16
  gemm_k<64,1><<<dim3(MPN / 128, 2), 256, 0, stream>>>(
      xbf, Wnet, bne, hbf, nullptr, nullptr, nullptr, nullptr, NN, 256, 128, 0, 0, 0);
  // edge encoder: ef = relu(edge_attr @ Wee + bee) -> bf16, CSR order via A-gather
  gemm_k<32,1,1><<<dim3(MPE / 128, 2), 256, 0, stream>>>(
      eabf, Weet, bee, efp, nullptr, nullptr, eidp, nullptr, EE, 256, 32, 0, 0, 0);

  for(int l = 0; l < 3; ++l){
    // fused q|skip|qWe (fp32) + k|v (bf16) slab
    gemm_k<64,0><<<dim3(MPN / 128, 10), 256, 0, stream>>>(
        hbf, Wcat + (size_t)l * 1280 * 256, biasc + (size_t)l * 1280, slab,
        nullptr, nullptr, nullptr, kvbf, NN, 768, 256, 0, 0, 0);
    // per-node attention: scores + exp + weighted sums (pre-divided by denom)
    node_pass_k<<<NN / 4, 256, 0, stream>>>(slab, efp, kvbf, srcp, offs, accv, aggef);
    // out = accv + aggef@We + skip  (+relu, bf16 for layers 0,1; fp32 out for layer 2)
    if(l < 2)
      gemm_k<64,3><<<dim3(MPN / 128, 2), 256, 0, stream>>>(
          aggef, Wet + (size_t)l * 256 * 256, nullptr, hbf,
          accv, slab, nullptr, nullptr, NN, 256, 256, 0, 0, 0);
    else
      gemm_k<64,4><<<dim3(MPN / 128, 2), 256, 0, stream>>>(
          aggef, Wet + (size_t)l * 256 * 256, nullptr, d_out,
          accv, slab, nullptr, nullptr, NN, 256, 256, 0, 0, 0);
  }
}